// Round 3
// baseline (19640.768 us; speedup 1.0000x reference)
//
#include <hip/hip_runtime.h>
#include <hip/hip_cooperative_groups.h>

namespace cg = cooperative_groups;

#define B 128
#define N 64
#define D 20
#define H 256
#define WMH 1024
#define CAUG 21
#define SIG 231
#define C 232
#define CP 240          // padded C
#define KA 288          // augmented K (256 + bias row + pad)
#define NSEG 63
#define NPH 126
#define HSTEP (1.0f/63.0f)
#define EPS 1e-5f

typedef __attribute__((ext_vector_type(8))) short short8;
typedef __attribute__((ext_vector_type(4))) float f32x4;

__device__ inline short f2bf(float f) {
  unsigned int u = __float_as_uint(f);
  unsigned int r = (u + 0x7fffu + ((u >> 16) & 1u)) >> 16;
  return (short)r;
}
__device__ inline float bf2f(short h) {
  return __uint_as_float(((unsigned int)(unsigned short)h) << 16);
}
#define MFMA16(a, b, c) __builtin_amdgcn_mfma_f32_16x16x32_bf16((a), (b), (c), 0, 0, 0)

// ---------------------------------------------------------------------------
// Kernel 1: depth-2 log-signature + LayerNorm -> y (B,N,C)
// ---------------------------------------------------------------------------
__global__ __launch_bounds__(256) void k_logsig(const float* __restrict__ x,
                                                const float* __restrict__ sg,
                                                const float* __restrict__ sb,
                                                float* __restrict__ y) {
  __shared__ float yb[N][C];
  int b = blockIdx.x, tid = threadIdx.x;
  for (int ii = tid; ii < N * CAUG; ii += 256) {
    int n = ii / CAUG, j = ii % CAUG;
    float v = (j == 0) ? (n * (1.0f / 63.0f)) : x[(b * N + n) * D + (j - 1)];
    yb[n][1 + j] = v;
  }
  __syncthreads();
  if (tid < 210) {
    int i = 0, rem = tid;
    while (rem >= (CAUG - 1) - i) { rem -= (CAUG - 1) - i; i++; }
    int j = i + 1 + rem;
    float acc = 0.f, pi_prev = 0.f, pj_prev = 0.f;
    for (int n = 0; n < N; n++) {
      float pi = yb[n][1 + i], pj = yb[n][1 + j];
      float di = pi - pi_prev, dj = pj - pj_prev;
      acc += 0.5f * (pi_prev * dj - di * pj_prev);
      yb[n][1 + CAUG + tid] = acc;
      pi_prev = pi; pj_prev = pj;
    }
  }
  __syncthreads();
  int w = tid >> 6, l = tid & 63;
  for (int n = w; n < N; n += 4) {
    float s1 = 0.f, s2 = 0.f;
    for (int s = l; s < SIG; s += 64) { float v = yb[n][1 + s]; s1 += v; s2 += v * v; }
    for (int off = 32; off > 0; off >>= 1) { s1 += __shfl_down(s1, off); s2 += __shfl_down(s2, off); }
    s1 = __shfl(s1, 0); s2 = __shfl(s2, 0);
    float mean = s1 * (1.0f / SIG);
    float var  = s2 * (1.0f / SIG) - mean * mean;
    float rs = rsqrtf(var + EPS);
    float* yrow = y + ((size_t)b * N + n) * C;
    if (l == 0) yrow[0] = n * (1.0f / 63.0f);
    for (int s = l; s < SIG; s += 64)
      yrow[1 + s] = (yb[n][1 + s] - mean) * rs * sg[s] + sb[s];
  }
}

// ---------------------------------------------------------------------------
// Kernel 2: natural cubic spline -> d_knot, d_mid (NSEG, B, CP) zero-padded
// ---------------------------------------------------------------------------
__global__ __launch_bounds__(256) void k_spline(const float* __restrict__ y,
                                                float* __restrict__ dknot,
                                                float* __restrict__ dmid) {
  __shared__ float yb[N * C];
  __shared__ float cp_s[62], id_s[62];
  int b = blockIdx.x, tid = threadIdx.x;
  for (int ii = tid; ii < N * C; ii += 256) yb[ii] = y[(size_t)b * N * C + ii];
  if (tid == 0) {
    const float a = HSTEP / 6.f, bb = 2.f * HSTEP / 3.f;
    float id0 = 1.f / bb; id_s[0] = id0; cp_s[0] = a * id0;
    for (int j = 1; j < 62; j++) {
      float den = bb - a * cp_s[j - 1];
      float idj = 1.f / den; id_s[j] = idj; cp_s[j] = a * idj;
    }
  }
  __syncthreads();
  int c = tid;
  if (c >= 232 && c < CP) {
    for (int n = 0; n < NSEG; n++) {
      dknot[((size_t)n * B + b) * CP + c] = 0.f;
      dmid [((size_t)n * B + b) * CP + c] = 0.f;
    }
  } else if (c < 232) {
    const float a = HSTEP / 6.f;
    float dp[62];
    dp[0] = (yb[2 * C + c] - 2.f * yb[1 * C + c] + yb[0 * C + c]) * 63.0f * id_s[0];
#pragma unroll
    for (int j = 1; j < 62; j++) {
      float rj = (yb[(j + 2) * C + c] - 2.f * yb[(j + 1) * C + c] + yb[j * C + c]) * 63.0f;
      dp[j] = (rj - a * dp[j - 1]) * id_s[j];
    }
#pragma unroll
    for (int j = 60; j >= 0; j--) dp[j] -= cp_s[j] * dp[j + 1];
#pragma unroll
    for (int n = 0; n < NSEG; n++) {
      float Mn  = (n == 0)  ? 0.f : dp[n - 1];
      float Mn1 = (n == 62) ? 0.f : dp[n];
      float dy = (yb[(n + 1) * C + c] - yb[n * C + c]) * 63.0f;
      dknot[((size_t)n * B + b) * CP + c] = dy - (HSTEP / 6.f)  * (2.f * Mn + Mn1);
      dmid [((size_t)n * B + b) * CP + c] = dy + (HSTEP / 24.f) * (Mn - Mn1);
    }
  }
}

// ---------------------------------------------------------------------------
// Kernel 3: initial hidden state -> z (f32) and Xhi/Xlo (bf16 hi/lo split)
// ---------------------------------------------------------------------------
__global__ __launch_bounds__(256) void k_h0(const float* __restrict__ x,
                                            const float* __restrict__ hW1,
                                            const float* __restrict__ hb1,
                                            const float* __restrict__ hW2,
                                            const float* __restrict__ hb2,
                                            float* __restrict__ z,
                                            short* __restrict__ Xhi,
                                            short* __restrict__ Xlo) {
  __shared__ float r[H];
  int b = blockIdx.x, tid = threadIdx.x;
  float s = hb1[tid];
#pragma unroll
  for (int d = 0; d < D; d++) s += x[(size_t)(b * N) * D + d] * hW1[d * H + tid];
  r[tid] = fmaxf(s, 0.f);
  __syncthreads();
  float s2 = hb2[tid];
  for (int k = 0; k < H; k++) s2 += r[k] * hW2[k * H + tid];
  z[b * H + tid] = s2;
  short hi = f2bf(s2);
  Xhi[b * H + tid] = hi;
  Xlo[b * H + tid] = f2bf(s2 - bf2f(hi));
}

// ---------------------------------------------------------------------------
// Prep: transpose fW4 (256 x 59392) f32 -> W4T [h*240+c][288] bf16
// ---------------------------------------------------------------------------
__global__ __launch_bounds__(256) void k_prep_t(const float* __restrict__ fW4,
                                                short* __restrict__ W4T) {
  __shared__ float tile[64][65];
  int m0 = blockIdx.x * 64, k0 = blockIdx.y * 64;
  int lane = threadIdx.x & 63, wr = threadIdx.x >> 6;
#pragma unroll
  for (int j = 0; j < 16; j++) {
    int kk = wr * 16 + j;
    tile[kk][lane] = fW4[(size_t)(k0 + kk) * 59392 + m0 + lane];
  }
  __syncthreads();
#pragma unroll
  for (int j = 0; j < 16; j++) {
    int mloc = wr * 16 + j;
    int m = m0 + mloc;
    int hh = m / 232, cc = m - hh * 232;
    W4T[((size_t)hh * CP + cc) * KA + k0 + lane] = f2bf(tile[lane][mloc]);
  }
}

// Prep: fill k'=256 (bias), k'=257..287 zeros, and c>=232 zero rows of W4T
__global__ __launch_bounds__(256) void k_prep_pad(const float* __restrict__ fb4,
                                                  short* __restrict__ W4T) {
  int idx = blockIdx.x * 256 + threadIdx.x;
  const int partA = 61440 * 32;
  if (idx < partA) {
    int row = idx >> 5, j = idx & 31;
    int hh = row / CP, cc = row - hh * CP;
    short v = 0;
    if (j == 0 && cc < 232) v = f2bf(fb4[hh * 232 + cc]);
    W4T[(size_t)row * KA + 256 + j] = v;
  } else {
    int t = idx - partA;
    int k = t & 255; t >>= 8;
    int cc = 232 + (t & 7); int hh = t >> 3;
    W4T[((size_t)hh * CP + cc) * KA + k] = 0;
  }
}

// Prep: tiled transpose f32 (K x Nn) -> bf16 out[n][k]
__global__ __launch_bounds__(256) void k_prep_wt(const float* __restrict__ in,
                                                 short* __restrict__ out,
                                                 int K, int Nn) {
  __shared__ float tile[64][65];
  int n0 = blockIdx.x * 64, k0 = blockIdx.y * 64;
  int lane = threadIdx.x & 63, wr = threadIdx.x >> 6;
#pragma unroll
  for (int j = 0; j < 16; j++) {
    int kk = wr * 16 + j;
    tile[kk][lane] = in[(size_t)(k0 + kk) * Nn + n0 + lane];
  }
  __syncthreads();
#pragma unroll
  for (int j = 0; j < 16; j++) {
    int nl = wr * 16 + j;
    out[(size_t)(n0 + nl) * K + k0 + lane] = f2bf(tile[lane][nl]);
  }
}

// Prep: static part of frag-major t3aug (k'=256 bias=1, 257..287 = 0)
__global__ __launch_bounds__(128) void k_prep_t3pad(short* __restrict__ t3aug) {
  int r = threadIdx.x;
  if (r < 128) {
    int base = ((r >> 4) * 9 + 8) * 64 + (r & 15);
#pragma unroll
    for (int q = 0; q < 4; q++)
#pragma unroll
      for (int j = 0; j < 8; j++)
        t3aug[(size_t)(base + q * 16) * 8 + j] = (q == 0 && j == 0) ? (short)0x3F80 : (short)0;
  }
}

// Prep: zero LN-stats region
__global__ __launch_bounds__(256) void k_prep_zero(float* __restrict__ p) {
  p[blockIdx.x * 256 + threadIdx.x] = 0.f;
}

// ---------------------------------------------------------------------------
// THE persistent cooperative scan kernel: 256 blocks x 512 threads.
// Per phase: S1 L1-GEMM+stats | S2 LN1+L2-GEMM+stats | S3 LN2+L3-GEMM->t3 |
//            S4 register-resident-W4 MFMA contraction + z update.
// ---------------------------------------------------------------------------
__global__ __launch_bounds__(512, 2) void k_scan(
    const short* __restrict__ W1T, const float* __restrict__ fb1,
    const float* __restrict__ g1,  const float* __restrict__ be1,
    const short* __restrict__ W2T, const float* __restrict__ fb2,
    const float* __restrict__ g2,  const float* __restrict__ be2,
    const short* __restrict__ W3T, const float* __restrict__ fb3,
    const short* __restrict__ W4T,
    const float* __restrict__ dknot, const float* __restrict__ dmid,
    float* __restrict__ z, short* __restrict__ Xhi, short* __restrict__ Xlo,
    float* __restrict__ T1, float* __restrict__ T2, short* __restrict__ t3aug,
    float* __restrict__ stats1, float* __restrict__ stats2) {
  cg::grid_group grid = cg::this_grid();
  const int blk = blockIdx.x;
  const int tid = threadIdx.x;
  const int wave = tid >> 6, lane = tid & 63;
  const int lm = lane & 15, q = lane >> 4;

  __shared__ union SB {
    short sbuf[36864];     // frag-major t3aug copy (73728 B)
    float red2[8][256];    // S2/S3 cross-wave k-split reduce
  } sb;
  __shared__ float red4[8][128];

  // --- persistent B-fragments: this block's W4 slice lives in registers ---
  const int nts = (wave < 7) ? 2 : 1;
  const int nt0 = wave * 2;
  short8 bfr[2][9];
  for (int t = 0; t < nts; t++) {
    const short* wp = W4T + ((size_t)blk * CP + (nt0 + t) * 16 + lm) * KA + q * 8;
#pragma unroll
    for (int kc = 0; kc < 9; kc++)
      bfr[t][kc] = *(const short8*)(wp + kc * 32);
  }

  for (int p = 0; p < NPH; p++) {
    const int seg = p >> 1, pm = p & 1;
    const float* dX = (pm ? dmid : dknot) + (size_t)seg * B * CP;
    const float scale = pm ? HSTEP : 0.5f * HSTEP;
    float* s1p = stats1 + p * (B * 2);
    float* s2p = stats2 + p * (B * 2);

    // ---- S1: T1 = X @ W1 + fb1 (X = Xhi+Xlo), 64 blocks x 16 cols ----
    if (blk < 64) {
      const int n0 = blk * 16;
      const int arow = wave * 16 + lm;
      const short* xh = Xhi + arow * H;
      const short* xl = Xlo + arow * H;
      const short* wb = W1T + (size_t)(n0 + lm) * H;
      f32x4 acc = {0.f, 0.f, 0.f, 0.f};
#pragma unroll
      for (int kc = 0; kc < 8; kc++) {
        short8 bw = *(const short8*)(wb + kc * 32 + q * 8);
        short8 ah = *(const short8*)(xh + kc * 32 + q * 8);
        short8 al = *(const short8*)(xl + kc * 32 + q * 8);
        acc = MFMA16(ah, bw, acc);
        acc = MFMA16(al, bw, acc);
      }
      float fb = fb1[n0 + lm];
#pragma unroll
      for (int r = 0; r < 4; r++) {
        int row = wave * 16 + q * 4 + r;
        float v = acc[r] + fb;
        T1[(size_t)row * WMH + n0 + lm] = v;
        float s = v, ss = v * v;
        s += __shfl_xor(s, 1); ss += __shfl_xor(ss, 1);
        s += __shfl_xor(s, 2); ss += __shfl_xor(ss, 2);
        s += __shfl_xor(s, 4); ss += __shfl_xor(ss, 4);
        s += __shfl_xor(s, 8); ss += __shfl_xor(ss, 8);
        if (lm == 0) {
          atomicAdd(&s1p[row * 2], s);
          atomicAdd(&s1p[row * 2 + 1], ss);
        }
      }
    }
    grid.sync();

    // ---- S2: T2 = relu(LN1(T1)) @ W2 + fb2, 128 blocks (8m x 16n) ----
    if (blk < 128) {
      const int m = blk >> 4, n = blk & 15;
      const int row = m * 16 + lm;
      float mean = s1p[row * 2] * (1.f / WMH);
      float var  = s1p[row * 2 + 1] * (1.f / WMH) - mean * mean;
      float rsv  = rsqrtf(var + EPS);
      f32x4 acc = {0.f, 0.f, 0.f, 0.f};
#pragma unroll
      for (int kc = 0; kc < 4; kc++) {
        int kg = wave * 128 + kc * 32 + q * 8;
        const float* tp = T1 + (size_t)row * WMH + kg;
        short8 ah, al;
#pragma unroll
        for (int j = 0; j < 8; j++) {
          float a = fmaxf((tp[j] - mean) * rsv * g1[kg + j] + be1[kg + j], 0.f);
          short hi = f2bf(a);
          ah[j] = hi;
          al[j] = f2bf(a - bf2f(hi));
        }
        short8 bw = *(const short8*)(W2T + (size_t)(n * 16 + lm) * WMH + kg);
        acc = MFMA16(ah, bw, acc);
        acc = MFMA16(al, bw, acc);
      }
#pragma unroll
      for (int r = 0; r < 4; r++) sb.red2[wave][(q * 4 + r) * 16 + lm] = acc[r];
      __syncthreads();
      if (tid < 256) {
        int ri = tid >> 4, ci = tid & 15;
        float v = fb2[n * 16 + ci];
#pragma unroll
        for (int w = 0; w < 8; w++) v += sb.red2[w][tid];
        T2[(size_t)(m * 16 + ri) * H + n * 16 + ci] = v;
        float s = v, ss = v * v;
        s += __shfl_xor(s, 1); ss += __shfl_xor(ss, 1);
        s += __shfl_xor(s, 2); ss += __shfl_xor(ss, 2);
        s += __shfl_xor(s, 4); ss += __shfl_xor(ss, 4);
        s += __shfl_xor(s, 8); ss += __shfl_xor(ss, 8);
        if (ci == 0) {
          atomicAdd(&s2p[(m * 16 + ri) * 2], s);
          atomicAdd(&s2p[(m * 16 + ri) * 2 + 1], ss);
        }
      }
    }
    grid.sync();

    // ---- S3: t3 = relu(relu(LN2(T2)) @ W3 + fb3) -> frag-major bf16 ----
    if (blk < 128) {
      const int m = blk >> 4, n = blk & 15;
      const int row = m * 16 + lm;
      float mean = s2p[row * 2] * (1.f / H);
      float var  = s2p[row * 2 + 1] * (1.f / H) - mean * mean;
      float rsv  = rsqrtf(var + EPS);
      int kg = wave * 32 + q * 8;
      const float* tp = T2 + (size_t)row * H + kg;
      short8 ah, al;
#pragma unroll
      for (int j = 0; j < 8; j++) {
        float a = fmaxf((tp[j] - mean) * rsv * g2[kg + j] + be2[kg + j], 0.f);
        short hi = f2bf(a);
        ah[j] = hi;
        al[j] = f2bf(a - bf2f(hi));
      }
      short8 bw = *(const short8*)(W3T + (size_t)(n * 16 + lm) * H + kg);
      f32x4 acc = {0.f, 0.f, 0.f, 0.f};
      acc = MFMA16(ah, bw, acc);
      acc = MFMA16(al, bw, acc);
#pragma unroll
      for (int r = 0; r < 4; r++) sb.red2[wave][(q * 4 + r) * 16 + lm] = acc[r];
      __syncthreads();
      if (tid < 256) {
        int ri = tid >> 4, ci = tid & 15;
        float v = fb3[n * 16 + ci];
#pragma unroll
        for (int w = 0; w < 8; w++) v += sb.red2[w][tid];
        v = fmaxf(v, 0.f);
        // frag-major write: r_glob = m*16+ri, k_glob = n*16+ci
        int kglob = n * 16 + ci;
        int d = (m * 9 + (kglob >> 5)) * 64 + ((kglob >> 3) & 3) * 16 + ri;
        t3aug[(size_t)d * 8 + (kglob & 7)] = f2bf(v);
      }
    }
    grid.sync();

    // ---- S4: contraction, all 256 blocks (h = blk), W4 in registers ----
    {
      const int h = blk;
#pragma unroll
      for (int i = 0; i < 9; i++) {
        int u = i * 512 + tid;
        *(short8*)(sb.sbuf + (size_t)u * 8) = *(const short8*)(t3aug + (size_t)u * 8);
      }
      __syncthreads();
      for (int m = 0; m < 8; m++) {
        short8 afr[9];
#pragma unroll
        for (int kc = 0; kc < 9; kc++)
          afr[kc] = *(const short8*)(sb.sbuf + (size_t)((m * 9 + kc) * 64 + lane) * 8);
        f32x4 acc0 = {0.f, 0.f, 0.f, 0.f}, acc1 = {0.f, 0.f, 0.f, 0.f};
#pragma unroll
        for (int kc = 0; kc < 9; kc++) {
          acc0 = MFMA16(afr[kc], bfr[0][kc], acc0);
          if (nts > 1) acc1 = MFMA16(afr[kc], bfr[1][kc], acc1);
        }
        float part[4];
#pragma unroll
        for (int r = 0; r < 4; r++) {
          int row = m * 16 + q * 4 + r;
          float pv = acc0[r] * dX[(size_t)row * CP + nt0 * 16 + lm];
          if (nts > 1) pv += acc1[r] * dX[(size_t)row * CP + (nt0 + 1) * 16 + lm];
          part[r] = pv;
        }
#pragma unroll
        for (int r = 0; r < 4; r++) {
          part[r] += __shfl_xor(part[r], 1);
          part[r] += __shfl_xor(part[r], 2);
          part[r] += __shfl_xor(part[r], 4);
          part[r] += __shfl_xor(part[r], 8);
        }
        if (lm == 0) {
#pragma unroll
          for (int r = 0; r < 4; r++) red4[wave][m * 16 + q * 4 + r] = part[r];
        }
      }
      __syncthreads();
      if (tid < 128) {
        int row = tid;
        float s = 0.f;
#pragma unroll
        for (int w = 0; w < 8; w++) s += red4[w][row];
        float zo = z[(size_t)row * H + h] + scale * s;
        if (pm) z[(size_t)row * H + h] = zo;
        short hi = f2bf(zo);
        Xhi[(size_t)row * H + h] = hi;
        Xlo[(size_t)row * H + h] = f2bf(zo - bf2f(hi));
      }
    }
    grid.sync();
  }
}

// ---------------------------------------------------------------------------
// Kernel 6: output heads
// ---------------------------------------------------------------------------
__global__ __launch_bounds__(256) void k_final(const float* __restrict__ z,
    const float* __restrict__ yW1, const float* __restrict__ yb1,
    const float* __restrict__ yW2, const float* __restrict__ yb2,
    const float* __restrict__ zW1, const float* __restrict__ zb1,
    const float* __restrict__ zW2, const float* __restrict__ zb2,
    float* __restrict__ out) {
  __shared__ float ht[H];
  __shared__ float ry[128];
  __shared__ float rz[H];
  int b = blockIdx.x, tid = threadIdx.x;
  ht[tid] = z[(size_t)b * H + tid];
  __syncthreads();
  if (tid < 128) {
    float s = yb1[tid];
    for (int k = 0; k < H; k++) s += ht[k] * yW1[k * 128 + tid];
    ry[tid] = fmaxf(s, 0.f);
  }
  {
    float s = zb1[tid];
    for (int k = 0; k < H; k++) s += ht[k] * zW1[k * H + tid];
    rz[tid] = fmaxf(s, 0.f);
  }
  __syncthreads();
  if (tid < 64) {
    float sv = ry[tid] * yW2[tid] + ry[tid + 64] * yW2[tid + 64];
    for (int off = 32; off > 0; off >>= 1) sv += __shfl_down(sv, off);
    if (tid == 0) out[b] = sv + yb2[0];
  }
  if (tid < D) {
    float s = zb2[tid];
    for (int k = 0; k < H; k++) s += rz[k] * zW2[k * D + tid];
    out[B + b * D + tid] = s;
  }
  out[B + B * D + (size_t)b * H + tid] = ht[tid];
}

// ---------------------------------------------------------------------------
extern "C" void kernel_launch(void* const* d_in, const int* in_sizes, int n_in,
                              void* d_out, int out_size, void* d_ws, size_t ws_size,
                              hipStream_t stream) {
  const float* x   = (const float*)d_in[0];
  const float* hW1 = (const float*)d_in[1];
  const float* hb1 = (const float*)d_in[2];
  const float* hW2 = (const float*)d_in[3];
  const float* hb2 = (const float*)d_in[4];
  const float* fW1 = (const float*)d_in[5];
  const float* fb1 = (const float*)d_in[6];
  const float* g1  = (const float*)d_in[7];
  const float* be1 = (const float*)d_in[8];
  const float* fW2 = (const float*)d_in[9];
  const float* fb2 = (const float*)d_in[10];
  const float* g2  = (const float*)d_in[11];
  const float* be2 = (const float*)d_in[12];
  const float* fW3 = (const float*)d_in[13];
  const float* fb3 = (const float*)d_in[14];
  const float* fW4 = (const float*)d_in[15];
  const float* fb4 = (const float*)d_in[16];
  const float* yW1 = (const float*)d_in[17];
  const float* yb1 = (const float*)d_in[18];
  const float* yW2 = (const float*)d_in[19];
  const float* yb2 = (const float*)d_in[20];
  const float* zW1 = (const float*)d_in[21];
  const float* zb1 = (const float*)d_in[22];
  const float* zW2 = (const float*)d_in[23];
  const float* zb2 = (const float*)d_in[24];
  const float* sg  = (const float*)d_in[25];
  const float* sb  = (const float*)d_in[26];

  float* ws     = (float*)d_ws;
  float* dknot  = ws;                              // 1,935,360 f
  float* dmid   = dknot + (size_t)NSEG * B * CP;   // 1,935,360 f
  float* z      = dmid + (size_t)NSEG * B * CP;    // 32,768 f
  float* T1     = z + B * H;                       // 131,072 f
  float* T2     = T1 + B * WMH;                    // 32,768 f
  float* stats1 = T2 + B * H;                      // 32,256 f
  float* stats2 = stats1 + NPH * B * 2;            // 32,256 f
  short* Xhi    = (short*)(stats2 + NPH * B * 2);  // 32,768 s
  short* Xlo    = Xhi + B * H;                     // 32,768 s
  short* t3aug  = Xlo + B * H;                     // 36,864 s
  short* w1T    = t3aug + B * KA;                  // 262,144 s
  short* w2T    = w1T + H * WMH;                   // 262,144 s
  short* w3T    = w2T + H * WMH;                   // 65,536 s
  short* W4T    = w3T + H * H;                     // 17,694,720 s
  float* y      = (float*)W4T;                     // temp alias (dead before W4T built)

  hipLaunchKernelGGL(k_logsig, dim3(B), dim3(256), 0, stream, x, sg, sb, y);
  hipLaunchKernelGGL(k_spline, dim3(B), dim3(256), 0, stream, y, dknot, dmid);
  hipLaunchKernelGGL(k_h0,     dim3(B), dim3(256), 0, stream, x, hW1, hb1, hW2, hb2, z, Xhi, Xlo);
  hipLaunchKernelGGL(k_prep_t,   dim3(928, 4), dim3(256), 0, stream, fW4, W4T);
  hipLaunchKernelGGL(k_prep_pad, dim3(9728),   dim3(256), 0, stream, fb4, W4T);
  hipLaunchKernelGGL(k_prep_wt,  dim3(16, 4),  dim3(256), 0, stream, fW1, w1T, H, WMH);
  hipLaunchKernelGGL(k_prep_wt,  dim3(4, 16),  dim3(256), 0, stream, fW2, w2T, WMH, H);
  hipLaunchKernelGGL(k_prep_wt,  dim3(4, 4),   dim3(256), 0, stream, fW3, w3T, H, H);
  hipLaunchKernelGGL(k_prep_t3pad, dim3(1), dim3(128), 0, stream, t3aug);
  hipLaunchKernelGGL(k_prep_zero, dim3(2 * NPH), dim3(256), 0, stream, stats1);

  void* args[] = {
    (void*)&w1T, (void*)&fb1, (void*)&g1, (void*)&be1,
    (void*)&w2T, (void*)&fb2, (void*)&g2, (void*)&be2,
    (void*)&w3T, (void*)&fb3, (void*)&W4T,
    (void*)&dknot, (void*)&dmid,
    (void*)&z, (void*)&Xhi, (void*)&Xlo,
    (void*)&T1, (void*)&T2, (void*)&t3aug,
    (void*)&stats1, (void*)&stats2
  };
  hipLaunchCooperativeKernel((const void*)k_scan, dim3(256), dim3(512), args, 0, stream);

  hipLaunchKernelGGL(k_final, dim3(B), dim3(256), 0, stream, z,
                     yW1, yb1, yW2, yb2, zW1, zb1, zW2, zb2, (float*)d_out);
}

// Round 4
// 13255.734 us; speedup vs baseline: 1.4817x; 1.4817x over previous
//
#include <hip/hip_runtime.h>

#define B 128
#define N 64
#define D 20
#define H 256
#define WMH 1024
#define CAUG 21
#define SIG 231
#define C 232
#define CP 240          // padded C
#define KA 288          // augmented K (256 + bias row + pad)
#define NSEG 63
#define NPH 126
#define HSTEP (1.0f/63.0f)
#define EPS 1e-5f

typedef __attribute__((ext_vector_type(8))) short short8;
typedef __attribute__((ext_vector_type(4))) float f32x4;

__device__ inline short f2bf(float f) {
  unsigned int u = __float_as_uint(f);
  unsigned int r = (u + 0x7fffu + ((u >> 16) & 1u)) >> 16;
  return (short)r;
}
__device__ inline float bf2f(short h) {
  return __uint_as_float(((unsigned int)(unsigned short)h) << 16);
}
#define MFMA16(a, b, c) __builtin_amdgcn_mfma_f32_16x16x32_bf16((a), (b), (c), 0, 0, 0)

// flag-sync primitives (device-scope; co-residency guaranteed by coop launch)
__device__ inline void fs_wait(int* ctr, int target) {
  if (threadIdx.x == 0) {
    while (__hip_atomic_load(ctr, __ATOMIC_ACQUIRE, __HIP_MEMORY_SCOPE_AGENT) < target)
      __builtin_amdgcn_s_sleep(1);
  }
  __syncthreads();
}
__device__ inline void fs_signal(int* ctr) {
  __syncthreads();
  if (threadIdx.x == 0)
    __hip_atomic_fetch_add(ctr, 1, __ATOMIC_RELEASE, __HIP_MEMORY_SCOPE_AGENT);
}

// ---------------------------------------------------------------------------
// Kernel 1: depth-2 log-signature + LayerNorm -> y (B,N,C)
// ---------------------------------------------------------------------------
__global__ __launch_bounds__(256) void k_logsig(const float* __restrict__ x,
                                                const float* __restrict__ sg,
                                                const float* __restrict__ sb,
                                                float* __restrict__ y) {
  __shared__ float yb[N][C];
  int b = blockIdx.x, tid = threadIdx.x;
  for (int ii = tid; ii < N * CAUG; ii += 256) {
    int n = ii / CAUG, j = ii % CAUG;
    float v = (j == 0) ? (n * (1.0f / 63.0f)) : x[(b * N + n) * D + (j - 1)];
    yb[n][1 + j] = v;
  }
  __syncthreads();
  if (tid < 210) {
    int i = 0, rem = tid;
    while (rem >= (CAUG - 1) - i) { rem -= (CAUG - 1) - i; i++; }
    int j = i + 1 + rem;
    float acc = 0.f, pi_prev = 0.f, pj_prev = 0.f;
    for (int n = 0; n < N; n++) {
      float pi = yb[n][1 + i], pj = yb[n][1 + j];
      float di = pi - pi_prev, dj = pj - pj_prev;
      acc += 0.5f * (pi_prev * dj - di * pj_prev);
      yb[n][1 + CAUG + tid] = acc;
      pi_prev = pi; pj_prev = pj;
    }
  }
  __syncthreads();
  int w = tid >> 6, l = tid & 63;
  for (int n = w; n < N; n += 4) {
    float s1 = 0.f, s2 = 0.f;
    for (int s = l; s < SIG; s += 64) { float v = yb[n][1 + s]; s1 += v; s2 += v * v; }
    for (int off = 32; off > 0; off >>= 1) { s1 += __shfl_down(s1, off); s2 += __shfl_down(s2, off); }
    s1 = __shfl(s1, 0); s2 = __shfl(s2, 0);
    float mean = s1 * (1.0f / SIG);
    float var  = s2 * (1.0f / SIG) - mean * mean;
    float rs = rsqrtf(var + EPS);
    float* yrow = y + ((size_t)b * N + n) * C;
    if (l == 0) yrow[0] = n * (1.0f / 63.0f);
    for (int s = l; s < SIG; s += 64)
      yrow[1 + s] = (yb[n][1 + s] - mean) * rs * sg[s] + sb[s];
  }
}

// ---------------------------------------------------------------------------
// Kernel 2: natural cubic spline -> d_knot, d_mid (NSEG, B, CP) zero-padded
// ---------------------------------------------------------------------------
__global__ __launch_bounds__(256) void k_spline(const float* __restrict__ y,
                                                float* __restrict__ dknot,
                                                float* __restrict__ dmid) {
  __shared__ float yb[N * C];
  __shared__ float cp_s[62], id_s[62];
  int b = blockIdx.x, tid = threadIdx.x;
  for (int ii = tid; ii < N * C; ii += 256) yb[ii] = y[(size_t)b * N * C + ii];
  if (tid == 0) {
    const float a = HSTEP / 6.f, bb = 2.f * HSTEP / 3.f;
    float id0 = 1.f / bb; id_s[0] = id0; cp_s[0] = a * id0;
    for (int j = 1; j < 62; j++) {
      float den = bb - a * cp_s[j - 1];
      float idj = 1.f / den; id_s[j] = idj; cp_s[j] = a * idj;
    }
  }
  __syncthreads();
  int c = tid;
  if (c >= 232 && c < CP) {
    for (int n = 0; n < NSEG; n++) {
      dknot[((size_t)n * B + b) * CP + c] = 0.f;
      dmid [((size_t)n * B + b) * CP + c] = 0.f;
    }
  } else if (c < 232) {
    const float a = HSTEP / 6.f;
    float dp[62];
    dp[0] = (yb[2 * C + c] - 2.f * yb[1 * C + c] + yb[0 * C + c]) * 63.0f * id_s[0];
#pragma unroll
    for (int j = 1; j < 62; j++) {
      float rj = (yb[(j + 2) * C + c] - 2.f * yb[(j + 1) * C + c] + yb[j * C + c]) * 63.0f;
      dp[j] = (rj - a * dp[j - 1]) * id_s[j];
    }
#pragma unroll
    for (int j = 60; j >= 0; j--) dp[j] -= cp_s[j] * dp[j + 1];
#pragma unroll
    for (int n = 0; n < NSEG; n++) {
      float Mn  = (n == 0)  ? 0.f : dp[n - 1];
      float Mn1 = (n == 62) ? 0.f : dp[n];
      float dy = (yb[(n + 1) * C + c] - yb[n * C + c]) * 63.0f;
      dknot[((size_t)n * B + b) * CP + c] = dy - (HSTEP / 6.f)  * (2.f * Mn + Mn1);
      dmid [((size_t)n * B + b) * CP + c] = dy + (HSTEP / 24.f) * (Mn - Mn1);
    }
  }
}

// ---------------------------------------------------------------------------
// Kernel 3: initial hidden state -> z (f32) and Xhi/Xlo (bf16 hi/lo split)
// ---------------------------------------------------------------------------
__global__ __launch_bounds__(256) void k_h0(const float* __restrict__ x,
                                            const float* __restrict__ hW1,
                                            const float* __restrict__ hb1,
                                            const float* __restrict__ hW2,
                                            const float* __restrict__ hb2,
                                            float* __restrict__ z,
                                            short* __restrict__ Xhi,
                                            short* __restrict__ Xlo) {
  __shared__ float r[H];
  int b = blockIdx.x, tid = threadIdx.x;
  float s = hb1[tid];
#pragma unroll
  for (int d = 0; d < D; d++) s += x[(size_t)(b * N) * D + d] * hW1[d * H + tid];
  r[tid] = fmaxf(s, 0.f);
  __syncthreads();
  float s2 = hb2[tid];
  for (int k = 0; k < H; k++) s2 += r[k] * hW2[k * H + tid];
  z[b * H + tid] = s2;
  short hi = f2bf(s2);
  Xhi[b * H + tid] = hi;
  Xlo[b * H + tid] = f2bf(s2 - bf2f(hi));
}

// ---------------------------------------------------------------------------
// Prep: transpose fW4 (256 x 59392) f32 -> W4T [h*240+c][288] bf16
// ---------------------------------------------------------------------------
__global__ __launch_bounds__(256) void k_prep_t(const float* __restrict__ fW4,
                                                short* __restrict__ W4T) {
  __shared__ float tile[64][65];
  int m0 = blockIdx.x * 64, k0 = blockIdx.y * 64;
  int lane = threadIdx.x & 63, wr = threadIdx.x >> 6;
#pragma unroll
  for (int j = 0; j < 16; j++) {
    int kk = wr * 16 + j;
    tile[kk][lane] = fW4[(size_t)(k0 + kk) * 59392 + m0 + lane];
  }
  __syncthreads();
#pragma unroll
  for (int j = 0; j < 16; j++) {
    int mloc = wr * 16 + j;
    int m = m0 + mloc;
    int hh = m / 232, cc = m - hh * 232;
    W4T[((size_t)hh * CP + cc) * KA + k0 + lane] = f2bf(tile[lane][mloc]);
  }
}

// Prep: fill k'=256 (bias), k'=257..287 zeros, and c>=232 zero rows of W4T
__global__ __launch_bounds__(256) void k_prep_pad(const float* __restrict__ fb4,
                                                  short* __restrict__ W4T) {
  int idx = blockIdx.x * 256 + threadIdx.x;
  const int partA = 61440 * 32;
  if (idx < partA) {
    int row = idx >> 5, j = idx & 31;
    int hh = row / CP, cc = row - hh * CP;
    short v = 0;
    if (j == 0 && cc < 232) v = f2bf(fb4[hh * 232 + cc]);
    W4T[(size_t)row * KA + 256 + j] = v;
  } else {
    int t = idx - partA;
    int k = t & 255; t >>= 8;
    int cc = 232 + (t & 7); int hh = t >> 3;
    W4T[((size_t)hh * CP + cc) * KA + k] = 0;
  }
}

// Prep: tiled transpose f32 (K x Nn) -> bf16 out[n][k]
__global__ __launch_bounds__(256) void k_prep_wt(const float* __restrict__ in,
                                                 short* __restrict__ out,
                                                 int K, int Nn) {
  __shared__ float tile[64][65];
  int n0 = blockIdx.x * 64, k0 = blockIdx.y * 64;
  int lane = threadIdx.x & 63, wr = threadIdx.x >> 6;
#pragma unroll
  for (int j = 0; j < 16; j++) {
    int kk = wr * 16 + j;
    tile[kk][lane] = in[(size_t)(k0 + kk) * Nn + n0 + lane];
  }
  __syncthreads();
#pragma unroll
  for (int j = 0; j < 16; j++) {
    int nl = wr * 16 + j;
    out[(size_t)(n0 + nl) * K + k0 + lane] = f2bf(tile[lane][nl]);
  }
}

// Prep: static part of frag-major t3aug (k'=256 bias=1, 257..287 = 0)
__global__ __launch_bounds__(128) void k_prep_t3pad(short* __restrict__ t3aug) {
  int r = threadIdx.x;
  if (r < 128) {
    int base = ((r >> 4) * 9 + 8) * 64 + (r & 15);
#pragma unroll
    for (int q = 0; q < 4; q++)
#pragma unroll
      for (int j = 0; j < 8; j++)
        t3aug[(size_t)(base + q * 16) * 8 + j] = (q == 0 && j == 0) ? (short)0x3F80 : (short)0;
  }
}

// Prep: zero region
__global__ __launch_bounds__(256) void k_prep_zero(float* __restrict__ p) {
  p[blockIdx.x * 256 + threadIdx.x] = 0.f;
}

// ---------------------------------------------------------------------------
// Persistent cooperative scan: 256 blocks x 512 threads, flag-synced stages.
// S1 (blks 0-63):  T1 = X@W1+fb1 (n-split), + LN1 stats partials
// S2 (blks 0-127): T2 = relu(LN1(T1))@W2+fb2 (m,n-split), + LN2 stats
// S3 (blks 0-127): t3 = relu(relu(LN2(T2))@W3+fb3) -> frag-major bf16
// S4 (all 256):    z += scale * (t3aug @ W4[h]) . dX   (W4 in registers)
// ---------------------------------------------------------------------------
__global__ __launch_bounds__(512, 2) void k_scan(
    const short* __restrict__ W1T, const float* __restrict__ fb1,
    const float* __restrict__ g1,  const float* __restrict__ be1,
    const short* __restrict__ W2T, const float* __restrict__ fb2,
    const float* __restrict__ g2,  const float* __restrict__ be2,
    const short* __restrict__ W3T, const float* __restrict__ fb3,
    const short* __restrict__ W4T,
    const float* __restrict__ dknot, const float* __restrict__ dmid,
    float* __restrict__ z, short* __restrict__ Xhi, short* __restrict__ Xlo,
    float* __restrict__ T1, float* __restrict__ T2, short* __restrict__ t3aug,
    float* __restrict__ stats1, float* __restrict__ stats2,
    int* __restrict__ cnt) {
  const int blk = blockIdx.x;
  const int tid = threadIdx.x;
  const int wave = tid >> 6, lane = tid & 63;
  const int lm = lane & 15, q = lane >> 4;

  __shared__ float red2[8][256];
  __shared__ float red4[8][128];
  __shared__ short w1s[8 * 64 * 8];      //  8 KB, S1 slice (frag-major)
  __shared__ short w2s[32 * 64 * 8];     // 32 KB, S2 slice
  __shared__ short w3s[8 * 64 * 8];      //  8 KB, S3 slice

  int* c1 = cnt;        // target 64
  int* c2 = cnt + 128;  // target 128
  int* c3 = cnt + 256;  // target 128
  int* c4 = cnt + 384;  // target 256

  // --- persistent B-fragments: this block's W4 slice lives in registers ---
  const int nts = (wave < 7) ? 2 : 1;
  const int nt0 = wave * 2;
  short8 bfr[2][9];
  for (int t = 0; t < nts; t++) {
    const short* wp = W4T + ((size_t)blk * CP + (nt0 + t) * 16 + lm) * KA + q * 8;
#pragma unroll
    for (int kc = 0; kc < 9; kc++)
      bfr[t][kc] = *(const short8*)(wp + kc * 32);
  }

  // --- one-time LDS weight residency (frag-major layouts) ---
  if (blk < 64) {
    int n0 = blk * 16;
    int kc = tid >> 6;
    *(short8*)(w1s + (size_t)tid * 8) =
        *(const short8*)(W1T + (size_t)(n0 + lm) * H + kc * 32 + q * 8);
  }
  if (blk < 128) {
    int n = blk & 15;
#pragma unroll
    for (int r = 0; r < 4; r++) {
      int u = tid + r * 512;
      int wk = u >> 6, ln = u & 63, lmi = ln & 15, qi = ln >> 4;
      int wv = wk >> 2, kc = wk & 3;
      *(short8*)(w2s + (size_t)u * 8) =
          *(const short8*)(W2T + (size_t)(n * 16 + lmi) * WMH + wv * 128 + kc * 32 + qi * 8);
    }
    int wv = tid >> 6;
    *(short8*)(w3s + (size_t)tid * 8) =
        *(const short8*)(W3T + (size_t)(n * 16 + lm) * H + wv * 32 + q * 8);
  }
  __syncthreads();

  for (int p = 0; p < NPH; p++) {
    const int seg = p >> 1, pm = p & 1;
    const float* dX = (pm ? dmid : dknot) + (size_t)seg * B * CP;
    const float scale = pm ? HSTEP : 0.5f * HSTEP;
    float* s1p = stats1 + p * (B * 2);
    float* s2p = stats2 + p * (B * 2);

    // ---- S1 ----
    if (blk < 64) {
      if (p) fs_wait(&c4[p - 1], 256);
      const int n0 = blk * 16;
      const int arow = wave * 16 + lm;
      const short* xh = Xhi + arow * H;
      const short* xl = Xlo + arow * H;
      f32x4 acc = {0.f, 0.f, 0.f, 0.f};
#pragma unroll
      for (int kc = 0; kc < 8; kc++) {
        short8 bw = *(const short8*)(w1s + (size_t)(kc * 64 + lane) * 8);
        short8 ah = *(const short8*)(xh + kc * 32 + q * 8);
        short8 al = *(const short8*)(xl + kc * 32 + q * 8);
        acc = MFMA16(ah, bw, acc);
        acc = MFMA16(al, bw, acc);
      }
      float fb = fb1[n0 + lm];
#pragma unroll
      for (int r = 0; r < 4; r++) {
        int row = wave * 16 + q * 4 + r;
        float v = acc[r] + fb;
        T1[(size_t)row * WMH + n0 + lm] = v;
        float s = v, ss = v * v;
        s += __shfl_xor(s, 1); ss += __shfl_xor(ss, 1);
        s += __shfl_xor(s, 2); ss += __shfl_xor(ss, 2);
        s += __shfl_xor(s, 4); ss += __shfl_xor(ss, 4);
        s += __shfl_xor(s, 8); ss += __shfl_xor(ss, 8);
        if (lm == 0) {
          atomicAdd(&s1p[row * 2], s);
          atomicAdd(&s1p[row * 2 + 1], ss);
        }
      }
      fs_signal(&c1[p]);
    }

    // ---- S2 ----
    if (blk < 128) {
      fs_wait(&c1[p], 64);
      const int m = blk >> 4, n = blk & 15;
      const int row = m * 16 + lm;
      float mean = s1p[row * 2] * (1.f / WMH);
      float var  = s1p[row * 2 + 1] * (1.f / WMH) - mean * mean;
      float rsv  = rsqrtf(var + EPS);
      f32x4 acc = {0.f, 0.f, 0.f, 0.f};
#pragma unroll
      for (int kc = 0; kc < 4; kc++) {
        int kg = wave * 128 + kc * 32 + q * 8;
        const float* tp = T1 + (size_t)row * WMH + kg;
        short8 ah, al;
#pragma unroll
        for (int j = 0; j < 8; j++) {
          float a = fmaxf((tp[j] - mean) * rsv * g1[kg + j] + be1[kg + j], 0.f);
          short hi = f2bf(a);
          ah[j] = hi;
          al[j] = f2bf(a - bf2f(hi));
        }
        short8 bw = *(const short8*)(w2s + (size_t)((wave * 4 + kc) * 64 + lane) * 8);
        acc = MFMA16(ah, bw, acc);
        acc = MFMA16(al, bw, acc);
      }
#pragma unroll
      for (int r = 0; r < 4; r++) red2[wave][(q * 4 + r) * 16 + lm] = acc[r];
      __syncthreads();
      if (tid < 256) {
        int ri = tid >> 4, ci = tid & 15;
        float v = fb2[n * 16 + ci];
#pragma unroll
        for (int w = 0; w < 8; w++) v += red2[w][tid];
        T2[(size_t)(m * 16 + ri) * H + n * 16 + ci] = v;
        float s = v, ss = v * v;
        s += __shfl_xor(s, 1); ss += __shfl_xor(ss, 1);
        s += __shfl_xor(s, 2); ss += __shfl_xor(ss, 2);
        s += __shfl_xor(s, 4); ss += __shfl_xor(ss, 4);
        s += __shfl_xor(s, 8); ss += __shfl_xor(ss, 8);
        if (ci == 0) {
          atomicAdd(&s2p[(m * 16 + ri) * 2], s);
          atomicAdd(&s2p[(m * 16 + ri) * 2 + 1], ss);
        }
      }
      fs_signal(&c2[p]);
    }

    // ---- S3 ----
    if (blk < 128) {
      fs_wait(&c2[p], 128);
      const int m = blk >> 4, n = blk & 15;
      const int row = m * 16 + lm;
      float mean = s2p[row * 2] * (1.f / H);
      float var  = s2p[row * 2 + 1] * (1.f / H) - mean * mean;
      float rsv  = rsqrtf(var + EPS);
      int kg = wave * 32 + q * 8;
      const float* tp = T2 + (size_t)row * H + kg;
      short8 ah, al;
#pragma unroll
      for (int j = 0; j < 8; j++) {
        float a = fmaxf((tp[j] - mean) * rsv * g2[kg + j] + be2[kg + j], 0.f);
        short hi = f2bf(a);
        ah[j] = hi;
        al[j] = f2bf(a - bf2f(hi));
      }
      short8 bw = *(const short8*)(w3s + (size_t)(wave * 64 + lane) * 8);
      f32x4 acc = {0.f, 0.f, 0.f, 0.f};
      acc = MFMA16(ah, bw, acc);
      acc = MFMA16(al, bw, acc);
#pragma unroll
      for (int r = 0; r < 4; r++) red2[wave][(q * 4 + r) * 16 + lm] = acc[r];
      __syncthreads();
      if (tid < 256) {
        int ri = tid >> 4, ci = tid & 15;
        float v = fb3[n * 16 + ci];
#pragma unroll
        for (int w = 0; w < 8; w++) v += red2[w][tid];
        v = fmaxf(v, 0.f);
        int kglob = n * 16 + ci;
        int d = (m * 9 + (kglob >> 5)) * 64 + ((kglob >> 3) & 3) * 16 + ri;
        t3aug[(size_t)d * 8 + (kglob & 7)] = f2bf(v);
      }
      fs_signal(&c3[p]);
    }

    // ---- S4: all 256 blocks ----
    {
      fs_wait(&c3[p], 128);
      const int h = blk;
      for (int m = 0; m < 8; m++) {
        short8 afr[9];
#pragma unroll
        for (int kc = 0; kc < 9; kc++)
          afr[kc] = *(const short8*)(t3aug + (size_t)((m * 9 + kc) * 64 + lane) * 8);
        f32x4 acc0 = {0.f, 0.f, 0.f, 0.f}, acc1 = {0.f, 0.f, 0.f, 0.f};
#pragma unroll
        for (int kc = 0; kc < 9; kc++) {
          acc0 = MFMA16(afr[kc], bfr[0][kc], acc0);
          if (nts > 1) acc1 = MFMA16(afr[kc], bfr[1][kc], acc1);
        }
        float part[4];
#pragma unroll
        for (int r = 0; r < 4; r++) {
          int row = m * 16 + q * 4 + r;
          float pv = acc0[r] * dX[(size_t)row * CP + nt0 * 16 + lm];
          if (nts > 1) pv += acc1[r] * dX[(size_t)row * CP + (nt0 + 1) * 16 + lm];
          part[r] = pv;
        }
#pragma unroll
        for (int r = 0; r < 4; r++) {
          part[r] += __shfl_xor(part[r], 1);
          part[r] += __shfl_xor(part[r], 2);
          part[r] += __shfl_xor(part[r], 4);
          part[r] += __shfl_xor(part[r], 8);
        }
        if (lm == 0) {
#pragma unroll
          for (int r = 0; r < 4; r++) red4[wave][m * 16 + q * 4 + r] = part[r];
        }
      }
      __syncthreads();
      if (tid < 128) {
        int row = tid;
        float s = 0.f;
#pragma unroll
        for (int w = 0; w < 8; w++) s += red4[w][row];
        float zo = z[(size_t)row * H + h] + scale * s;
        if (pm) z[(size_t)row * H + h] = zo;
        short hi = f2bf(zo);
        Xhi[(size_t)row * H + h] = hi;
        Xlo[(size_t)row * H + h] = f2bf(zo - bf2f(hi));
      }
      fs_signal(&c4[p]);
    }
  }
}

// ---------------------------------------------------------------------------
// Kernel 6: output heads
// ---------------------------------------------------------------------------
__global__ __launch_bounds__(256) void k_final(const float* __restrict__ z,
    const float* __restrict__ yW1, const float* __restrict__ yb1,
    const float* __restrict__ yW2, const float* __restrict__ yb2,
    const float* __restrict__ zW1, const float* __restrict__ zb1,
    const float* __restrict__ zW2, const float* __restrict__ zb2,
    float* __restrict__ out) {
  __shared__ float ht[H];
  __shared__ float ry[128];
  __shared__ float rz[H];
  int b = blockIdx.x, tid = threadIdx.x;
  ht[tid] = z[(size_t)b * H + tid];
  __syncthreads();
  if (tid < 128) {
    float s = yb1[tid];
    for (int k = 0; k < H; k++) s += ht[k] * yW1[k * 128 + tid];
    ry[tid] = fmaxf(s, 0.f);
  }
  {
    float s = zb1[tid];
    for (int k = 0; k < H; k++) s += ht[k] * zW1[k * H + tid];
    rz[tid] = fmaxf(s, 0.f);
  }
  __syncthreads();
  if (tid < 64) {
    float sv = ry[tid] * yW2[tid] + ry[tid + 64] * yW2[tid + 64];
    for (int off = 32; off > 0; off >>= 1) sv += __shfl_down(sv, off);
    if (tid == 0) out[b] = sv + yb2[0];
  }
  if (tid < D) {
    float s = zb2[tid];
    for (int k = 0; k < H; k++) s += rz[k] * zW2[k * D + tid];
    out[B + b * D + tid] = s;
  }
  out[B + B * D + (size_t)b * H + tid] = ht[tid];
}

// ---------------------------------------------------------------------------
extern "C" void kernel_launch(void* const* d_in, const int* in_sizes, int n_in,
                              void* d_out, int out_size, void* d_ws, size_t ws_size,
                              hipStream_t stream) {
  const float* x   = (const float*)d_in[0];
  const float* hW1 = (const float*)d_in[1];
  const float* hb1 = (const float*)d_in[2];
  const float* hW2 = (const float*)d_in[3];
  const float* hb2 = (const float*)d_in[4];
  const float* fW1 = (const float*)d_in[5];
  const float* fb1 = (const float*)d_in[6];
  const float* g1  = (const float*)d_in[7];
  const float* be1 = (const float*)d_in[8];
  const float* fW2 = (const float*)d_in[9];
  const float* fb2 = (const float*)d_in[10];
  const float* g2  = (const float*)d_in[11];
  const float* be2 = (const float*)d_in[12];
  const float* fW3 = (const float*)d_in[13];
  const float* fb3 = (const float*)d_in[14];
  const float* fW4 = (const float*)d_in[15];
  const float* fb4 = (const float*)d_in[16];
  const float* yW1 = (const float*)d_in[17];
  const float* yb1 = (const float*)d_in[18];
  const float* yW2 = (const float*)d_in[19];
  const float* yb2 = (const float*)d_in[20];
  const float* zW1 = (const float*)d_in[21];
  const float* zb1 = (const float*)d_in[22];
  const float* zW2 = (const float*)d_in[23];
  const float* zb2 = (const float*)d_in[24];
  const float* sg  = (const float*)d_in[25];
  const float* sb  = (const float*)d_in[26];

  float* ws     = (float*)d_ws;
  float* dknot  = ws;                              // 1,935,360 f
  float* dmid   = dknot + (size_t)NSEG * B * CP;   // 1,935,360 f
  float* z      = dmid + (size_t)NSEG * B * CP;    // 32,768 f
  float* T1     = z + B * H;                       // 131,072 f
  float* T2     = T1 + B * WMH;                    // 32,768 f
  float* stats1 = T2 + B * H;                      // 32,256 f
  float* stats2 = stats1 + NPH * B * 2;            // 32,256 f
  int*   cnt    = (int*)(stats2 + NPH * B * 2);    // 512 i
  short* Xhi    = (short*)(cnt + 512);             // 32,768 s
  short* Xlo    = Xhi + B * H;                     // 32,768 s
  short* t3aug  = Xlo + B * H;                     // 36,864 s
  short* w1T    = t3aug + B * KA;                  // 262,144 s
  short* w2T    = w1T + H * WMH;                   // 262,144 s
  short* w3T    = w2T + H * WMH;                   // 65,536 s
  short* W4T    = w3T + H * H;                     // 17,694,720 s
  float* y      = (float*)W4T;                     // temp alias (dead before W4T built)

  hipLaunchKernelGGL(k_logsig, dim3(B), dim3(256), 0, stream, x, sg, sb, y);
  hipLaunchKernelGGL(k_spline, dim3(B), dim3(256), 0, stream, y, dknot, dmid);
  hipLaunchKernelGGL(k_h0,     dim3(B), dim3(256), 0, stream, x, hW1, hb1, hW2, hb2, z, Xhi, Xlo);
  hipLaunchKernelGGL(k_prep_t,   dim3(928, 4), dim3(256), 0, stream, fW4, W4T);
  hipLaunchKernelGGL(k_prep_pad, dim3(9728),   dim3(256), 0, stream, fb4, W4T);
  hipLaunchKernelGGL(k_prep_wt,  dim3(16, 4),  dim3(256), 0, stream, fW1, w1T, H, WMH);
  hipLaunchKernelGGL(k_prep_wt,  dim3(4, 16),  dim3(256), 0, stream, fW2, w2T, WMH, H);
  hipLaunchKernelGGL(k_prep_wt,  dim3(4, 4),   dim3(256), 0, stream, fW3, w3T, H, H);
  hipLaunchKernelGGL(k_prep_t3pad, dim3(1), dim3(128), 0, stream, t3aug);
  hipLaunchKernelGGL(k_prep_zero, dim3(2 * NPH), dim3(256), 0, stream, stats1);  // stats1+stats2
  hipLaunchKernelGGL(k_prep_zero, dim3(2), dim3(256), 0, stream, (float*)cnt);   // counters

  void* args[] = {
    (void*)&w1T, (void*)&fb1, (void*)&g1, (void*)&be1,
    (void*)&w2T, (void*)&fb2, (void*)&g2, (void*)&be2,
    (void*)&w3T, (void*)&fb3, (void*)&W4T,
    (void*)&dknot, (void*)&dmid,
    (void*)&z, (void*)&Xhi, (void*)&Xlo,
    (void*)&T1, (void*)&T2, (void*)&t3aug,
    (void*)&stats1, (void*)&stats2, (void*)&cnt
  };
  hipLaunchCooperativeKernel((const void*)k_scan, dim3(256), dim3(512), args, 0, stream);

  hipLaunchKernelGGL(k_final, dim3(B), dim3(256), 0, stream, z,
                     yW1, yb1, yW2, yb2, zW1, zb1, zW2, zb2, (float*)d_out);
}

// Round 5
// 7650.889 us; speedup vs baseline: 2.5671x; 1.7326x over previous
//
#include <hip/hip_runtime.h>

#define B 128
#define N 64
#define D 20
#define H 256
#define WMH 1024
#define CAUG 21
#define SIG 231
#define C 232
#define CP 240          // padded C
#define KA 288          // augmented K (256 + bias row + pad)
#define NSEG 63
#define NPH 126
#define HSTEP (1.0f/63.0f)
#define EPS 1e-5f

typedef __attribute__((ext_vector_type(8))) short short8;
typedef __attribute__((ext_vector_type(4))) float f32x4;

__device__ inline short f2bf(float f) {
  unsigned int u = __float_as_uint(f);
  unsigned int r = (u + 0x7fffu + ((u >> 16) & 1u)) >> 16;
  return (short)r;
}
__device__ inline float bf2f(short h) {
  return __uint_as_float(((unsigned int)(unsigned short)h) << 16);
}
__device__ inline float bflo(unsigned int w) { return __uint_as_float(w << 16); }
__device__ inline float bfhi(unsigned int w) { return __uint_as_float(w & 0xffff0000u); }
#define MFMA16(a, b, c) __builtin_amdgcn_mfma_f32_16x16x32_bf16((a), (b), (c), 0, 0, 0)

// --- coherent (device-scope, L2-bypassing) relaxed accesses: NO cache
// maintenance is ever triggered (no buffer_inv / buffer_wbl2).
__device__ inline unsigned int cloadu(const unsigned int* p) {
  return __hip_atomic_load(p, __ATOMIC_RELAXED, __HIP_MEMORY_SCOPE_AGENT);
}
__device__ inline void cstoreu(unsigned int* p, unsigned int v) {
  __hip_atomic_store(p, v, __ATOMIC_RELAXED, __HIP_MEMORY_SCOPE_AGENT);
}
__device__ inline int cloadi(const int* p) {
  return __hip_atomic_load(p, __ATOMIC_RELAXED, __HIP_MEMORY_SCOPE_AGENT);
}
__device__ inline void cstorei(int* p, int v) {
  __hip_atomic_store(p, v, __ATOMIC_RELAXED, __HIP_MEMORY_SCOPE_AGENT);
}

// wait until flags f[0..n) all >= v. Distinct slot per polling thread.
__device__ inline void waitflags(int* f, int n, int v) {
  for (int i = threadIdx.x; i < n; i += blockDim.x) {
    if (cloadi(f + i) >= v) continue;
    do { __builtin_amdgcn_s_sleep(2); } while (cloadi(f + i) < v);
  }
  __builtin_amdgcn_fence(__ATOMIC_ACQUIRE, "workgroup");   // s_waitcnt only
  __syncthreads();
}
// all threads call; thread 0 publishes after whole block's stores completed.
__device__ inline void signalflag(int* f, int v) {
  __builtin_amdgcn_fence(__ATOMIC_RELEASE, "workgroup");   // per-wave vmcnt drain
  __syncthreads();
  if (threadIdx.x == 0) cstorei(f, v);
}

// ---------------------------------------------------------------------------
// Kernel 1: depth-2 log-signature + LayerNorm -> y (B,N,C)
// ---------------------------------------------------------------------------
__global__ __launch_bounds__(256) void k_logsig(const float* __restrict__ x,
                                                const float* __restrict__ sg,
                                                const float* __restrict__ sb,
                                                float* __restrict__ y) {
  __shared__ float yb[N][C];
  int b = blockIdx.x, tid = threadIdx.x;
  for (int ii = tid; ii < N * CAUG; ii += 256) {
    int n = ii / CAUG, j = ii % CAUG;
    float v = (j == 0) ? (n * (1.0f / 63.0f)) : x[(b * N + n) * D + (j - 1)];
    yb[n][1 + j] = v;
  }
  __syncthreads();
  if (tid < 210) {
    int i = 0, rem = tid;
    while (rem >= (CAUG - 1) - i) { rem -= (CAUG - 1) - i; i++; }
    int j = i + 1 + rem;
    float acc = 0.f, pi_prev = 0.f, pj_prev = 0.f;
    for (int n = 0; n < N; n++) {
      float pi = yb[n][1 + i], pj = yb[n][1 + j];
      float di = pi - pi_prev, dj = pj - pj_prev;
      acc += 0.5f * (pi_prev * dj - di * pj_prev);
      yb[n][1 + CAUG + tid] = acc;
      pi_prev = pi; pj_prev = pj;
    }
  }
  __syncthreads();
  int w = tid >> 6, l = tid & 63;
  for (int n = w; n < N; n += 4) {
    float s1 = 0.f, s2 = 0.f;
    for (int s = l; s < SIG; s += 64) { float v = yb[n][1 + s]; s1 += v; s2 += v * v; }
    for (int off = 32; off > 0; off >>= 1) { s1 += __shfl_down(s1, off); s2 += __shfl_down(s2, off); }
    s1 = __shfl(s1, 0); s2 = __shfl(s2, 0);
    float mean = s1 * (1.0f / SIG);
    float var  = s2 * (1.0f / SIG) - mean * mean;
    float rs = rsqrtf(var + EPS);
    float* yrow = y + ((size_t)b * N + n) * C;
    if (l == 0) yrow[0] = n * (1.0f / 63.0f);
    for (int s = l; s < SIG; s += 64)
      yrow[1 + s] = (yb[n][1 + s] - mean) * rs * sg[s] + sb[s];
  }
}

// ---------------------------------------------------------------------------
// Kernel 2: natural cubic spline -> d_knot, d_mid (NSEG, B, CP) zero-padded
// ---------------------------------------------------------------------------
__global__ __launch_bounds__(256) void k_spline(const float* __restrict__ y,
                                                float* __restrict__ dknot,
                                                float* __restrict__ dmid) {
  __shared__ float yb[N * C];
  __shared__ float cp_s[62], id_s[62];
  int b = blockIdx.x, tid = threadIdx.x;
  for (int ii = tid; ii < N * C; ii += 256) yb[ii] = y[(size_t)b * N * C + ii];
  if (tid == 0) {
    const float a = HSTEP / 6.f, bb = 2.f * HSTEP / 3.f;
    float id0 = 1.f / bb; id_s[0] = id0; cp_s[0] = a * id0;
    for (int j = 1; j < 62; j++) {
      float den = bb - a * cp_s[j - 1];
      float idj = 1.f / den; id_s[j] = idj; cp_s[j] = a * idj;
    }
  }
  __syncthreads();
  int c = tid;
  if (c >= 232 && c < CP) {
    for (int n = 0; n < NSEG; n++) {
      dknot[((size_t)n * B + b) * CP + c] = 0.f;
      dmid [((size_t)n * B + b) * CP + c] = 0.f;
    }
  } else if (c < 232) {
    const float a = HSTEP / 6.f;
    float dp[62];
    dp[0] = (yb[2 * C + c] - 2.f * yb[1 * C + c] + yb[0 * C + c]) * 63.0f * id_s[0];
#pragma unroll
    for (int j = 1; j < 62; j++) {
      float rj = (yb[(j + 2) * C + c] - 2.f * yb[(j + 1) * C + c] + yb[j * C + c]) * 63.0f;
      dp[j] = (rj - a * dp[j - 1]) * id_s[j];
    }
#pragma unroll
    for (int j = 60; j >= 0; j--) dp[j] -= cp_s[j] * dp[j + 1];
#pragma unroll
    for (int n = 0; n < NSEG; n++) {
      float Mn  = (n == 0)  ? 0.f : dp[n - 1];
      float Mn1 = (n == 62) ? 0.f : dp[n];
      float dy = (yb[(n + 1) * C + c] - yb[n * C + c]) * 63.0f;
      dknot[((size_t)n * B + b) * CP + c] = dy - (HSTEP / 6.f)  * (2.f * Mn + Mn1);
      dmid [((size_t)n * B + b) * CP + c] = dy + (HSTEP / 24.f) * (Mn - Mn1);
    }
  }
}

// ---------------------------------------------------------------------------
// Kernel 3: initial hidden state -> z (f32) and Xu (packed hi|lo bf16)
// ---------------------------------------------------------------------------
__global__ __launch_bounds__(256) void k_h0(const float* __restrict__ x,
                                            const float* __restrict__ hW1,
                                            const float* __restrict__ hb1,
                                            const float* __restrict__ hW2,
                                            const float* __restrict__ hb2,
                                            float* __restrict__ z,
                                            unsigned int* __restrict__ Xu) {
  __shared__ float r[H];
  int b = blockIdx.x, tid = threadIdx.x;
  float s = hb1[tid];
#pragma unroll
  for (int d = 0; d < D; d++) s += x[(size_t)(b * N) * D + d] * hW1[d * H + tid];
  r[tid] = fmaxf(s, 0.f);
  __syncthreads();
  float s2 = hb2[tid];
  for (int k = 0; k < H; k++) s2 += r[k] * hW2[k * H + tid];
  z[b * H + tid] = s2;
  short hi = f2bf(s2);
  short lo = f2bf(s2 - bf2f(hi));
  Xu[b * H + tid] = ((unsigned int)(unsigned short)hi << 16) | (unsigned short)lo;
}

// ---------------------------------------------------------------------------
// Prep: transpose fW4 (256 x 59392) f32 -> W4T [h*240+c][288] bf16
// ---------------------------------------------------------------------------
__global__ __launch_bounds__(256) void k_prep_t(const float* __restrict__ fW4,
                                                short* __restrict__ W4T) {
  __shared__ float tile[64][65];
  int m0 = blockIdx.x * 64, k0 = blockIdx.y * 64;
  int lane = threadIdx.x & 63, wr = threadIdx.x >> 6;
#pragma unroll
  for (int j = 0; j < 16; j++) {
    int kk = wr * 16 + j;
    tile[kk][lane] = fW4[(size_t)(k0 + kk) * 59392 + m0 + lane];
  }
  __syncthreads();
#pragma unroll
  for (int j = 0; j < 16; j++) {
    int mloc = wr * 16 + j;
    int m = m0 + mloc;
    int hh = m / 232, cc = m - hh * 232;
    W4T[((size_t)hh * CP + cc) * KA + k0 + lane] = f2bf(tile[lane][mloc]);
  }
}

// Prep: fill k'=256 (bias), k'=257..287 zeros, and c>=232 zero rows of W4T
__global__ __launch_bounds__(256) void k_prep_pad(const float* __restrict__ fb4,
                                                  short* __restrict__ W4T) {
  int idx = blockIdx.x * 256 + threadIdx.x;
  const int partA = 61440 * 32;
  if (idx < partA) {
    int row = idx >> 5, j = idx & 31;
    int hh = row / CP, cc = row - hh * CP;
    short v = 0;
    if (j == 0 && cc < 232) v = f2bf(fb4[hh * 232 + cc]);
    W4T[(size_t)row * KA + 256 + j] = v;
  } else {
    int t = idx - partA;
    int k = t & 255; t >>= 8;
    int cc = 232 + (t & 7); int hh = t >> 3;
    W4T[((size_t)hh * CP + cc) * KA + k] = 0;
  }
}

// Prep: f32 -> bf16 flat convert
__global__ __launch_bounds__(256) void k_prep_w(const float* __restrict__ w,
                                                short* __restrict__ o, int n) {
  int i = blockIdx.x * 256 + threadIdx.x;
  if (i < n) o[i] = f2bf(w[i]);
}

// Prep: static part of frag-major t3aug (k'=256 bias=1, 257..287 = 0)
__global__ __launch_bounds__(128) void k_prep_t3pad(short* __restrict__ t3aug) {
  int r = threadIdx.x;
  if (r < 128) {
    int base = ((r >> 4) * 9 + 8) * 64 + (r & 15);
#pragma unroll
    for (int q = 0; q < 4; q++)
#pragma unroll
      for (int j = 0; j < 8; j++)
        t3aug[(size_t)(base + q * 16) * 8 + j] = (q == 0 && j == 0) ? (short)0x3F80 : (short)0;
  }
}

// Prep: zero region (used for flags)
__global__ __launch_bounds__(256) void k_prep_zero(int* __restrict__ p, int n) {
  int i = blockIdx.x * 256 + threadIdx.x;
  if (i < n) p[i] = 0;
}

// ---------------------------------------------------------------------------
// Persistent scan: 256 blocks x 512 threads, 2 flag-syncs per phase.
// Stage M (blocks 0..127, block=batch row): whole RDEFunc MLP, VALU,
//   LN stats block-local. Emits t3 row as frag-major packed bf16 (coherent).
// Stage C (all 256 blocks, h=blk): MFMA contraction with register-resident
//   W4 slice; z column lives in LDS across phases; emits Xu (coherent).
// ---------------------------------------------------------------------------
__global__ __launch_bounds__(512, 2) void k_scan(
    const short* __restrict__ w1b, const float* __restrict__ fb1,
    const float* __restrict__ g1,  const float* __restrict__ be1,
    const short* __restrict__ w2b, const float* __restrict__ fb2,
    const float* __restrict__ g2,  const float* __restrict__ be2,
    const short* __restrict__ w3b, const float* __restrict__ fb3,
    const short* __restrict__ W4T,
    const float* __restrict__ dknot, const float* __restrict__ dmid,
    float* __restrict__ z, unsigned int* __restrict__ Xu,
    unsigned int* __restrict__ t3u,
    int* __restrict__ flagsM, int* __restrict__ flagsC) {
  const int blk = blockIdx.x;
  const int tid = threadIdx.x;
  const int wave = tid >> 6, lane = tid & 63;
  const int lm = lane & 15, q = lane >> 4;

  __shared__ union {
    struct {
      float zsh[H]; float t1[WMH]; float t2[H];
      float red[4][H]; float wred[8][2]; float t3row[H];
    } m;
    short t3s[B * KA];               // 73728 B, stage-C A-operand copy
  } sm;
  __shared__ float red4[8][128];
  __shared__ float zcol[128];

  const unsigned int* w1u = (const unsigned int*)w1b;
  const unsigned int* w2u = (const unsigned int*)w2b;
  const unsigned int* w3u = (const unsigned int*)w3b;

  // persistent B-fragments: this block's W4 slice in registers
  const int nts = (wave < 7) ? 2 : 1;
  const int nt0 = wave * 2;
  short8 bfr[2][9];
  for (int t = 0; t < nts; t++) {
    const short* wp = W4T + ((size_t)blk * CP + (nt0 + t) * 16 + lm) * KA + q * 8;
#pragma unroll
    for (int kc = 0; kc < 9; kc++)
      bfr[t][kc] = *(const short8*)(wp + kc * 32);
  }
  // z column init (h0's kernel flushed at its end -> plain loads fine)
  if (tid < 128) zcol[tid] = z[(size_t)tid * H + blk];
  __syncthreads();

  for (int p = 0; p < NPH; p++) {
    const int seg = p >> 1, pm = p & 1;
    const float* dX = (pm ? dmid : dknot) + (size_t)seg * B * CP;
    const float scale = pm ? HSTEP : 0.5f * HSTEP;

    // ================= Stage M: MLP for batch row b = blk =================
    if (blk < B) {
      const int b = blk;
      if (p) waitflags(flagsC + (p - 1) * 256, 256, 1);
      if (tid < H) {
        unsigned int u = cloadu(Xu + b * H + tid);
        sm.m.zsh[tid] = __uint_as_float(u & 0xffff0000u) + __uint_as_float(u << 16);
      }
      __syncthreads();
      // layer 1: cols 2*tid, 2*tid+1
      const int n0 = tid * 2;
      float a0 = fb1[n0], a1 = fb1[n0 + 1];
#pragma unroll 4
      for (int k = 0; k < H; k++) {
        float zk = sm.m.zsh[k];
        unsigned int w = w1u[k * 512 + tid];
        a0 = fmaf(bflo(w), zk, a0);
        a1 = fmaf(bfhi(w), zk, a1);
      }
      {
        float s1 = a0 + a1, s2 = a0 * a0 + a1 * a1;
        for (int off = 32; off > 0; off >>= 1) { s1 += __shfl_down(s1, off); s2 += __shfl_down(s2, off); }
        if (lane == 0) { sm.m.wred[wave][0] = s1; sm.m.wred[wave][1] = s2; }
      }
      __syncthreads();
      {
        float S1 = 0, S2 = 0;
#pragma unroll
        for (int wq = 0; wq < 8; wq++) { S1 += sm.m.wred[wq][0]; S2 += sm.m.wred[wq][1]; }
        float mn = S1 * (1.f / WMH), vr = S2 * (1.f / WMH) - mn * mn, rs = rsqrtf(vr + EPS);
        sm.m.t1[n0]     = fmaxf((a0 - mn) * rs * g1[n0]     + be1[n0],     0.f);
        sm.m.t1[n0 + 1] = fmaxf((a1 - mn) * rs * g1[n0 + 1] + be1[n0 + 1], 0.f);
      }
      __syncthreads();
      // layer 2: 4-way k-split, cols nn, nn+1
      const int kq = tid >> 7, nn = (tid & 127) * 2;
      {
        float b0 = 0.f, b1v = 0.f;
        int k0 = kq * 256;
#pragma unroll 4
        for (int k = k0; k < k0 + 256; k++) {
          float tk = sm.m.t1[k];
          unsigned int w = w2u[k * 128 + (tid & 127)];
          b0  = fmaf(bflo(w), tk, b0);
          b1v = fmaf(bfhi(w), tk, b1v);
        }
        sm.m.red[kq][nn] = b0; sm.m.red[kq][nn + 1] = b1v;
      }
      __syncthreads();
      float a2 = 0.f;
      if (tid < H) a2 = fb2[tid] + sm.m.red[0][tid] + sm.m.red[1][tid] + sm.m.red[2][tid] + sm.m.red[3][tid];
      {
        float s1 = (tid < H) ? a2 : 0.f, s2 = (tid < H) ? a2 * a2 : 0.f;
        for (int off = 32; off > 0; off >>= 1) { s1 += __shfl_down(s1, off); s2 += __shfl_down(s2, off); }
        __syncthreads();
        if (lane == 0) { sm.m.wred[wave][0] = s1; sm.m.wred[wave][1] = s2; }
      }
      __syncthreads();
      {
        float S1 = 0, S2 = 0;
#pragma unroll
        for (int wq = 0; wq < 8; wq++) { S1 += sm.m.wred[wq][0]; S2 += sm.m.wred[wq][1]; }
        float mn = S1 * (1.f / H), vr = S2 * (1.f / H) - mn * mn, rs = rsqrtf(vr + EPS);
        if (tid < H) sm.m.t2[tid] = fmaxf((a2 - mn) * rs * g2[tid] + be2[tid], 0.f);
      }
      __syncthreads();
      // layer 3: 4-way k-split of K=256
      {
        float b0 = 0.f, b1v = 0.f;
        int k0 = kq * 64;
#pragma unroll 4
        for (int k = k0; k < k0 + 64; k++) {
          float tk = sm.m.t2[k];
          unsigned int w = w3u[k * 128 + (tid & 127)];
          b0  = fmaf(bflo(w), tk, b0);
          b1v = fmaf(bfhi(w), tk, b1v);
        }
        sm.m.red[kq][nn] = b0; sm.m.red[kq][nn + 1] = b1v;
      }
      __syncthreads();
      if (tid < H) {
        float a3 = fb3[tid] + sm.m.red[0][tid] + sm.m.red[1][tid] + sm.m.red[2][tid] + sm.m.red[3][tid];
        sm.m.t3row[tid] = fmaxf(a3, 0.f);
      }
      __syncthreads();
      if (tid < 128) {
        int ke = tid * 2;
        int kc = ke >> 5, q4 = (ke >> 3) & 3;
        int d = ((b >> 4) * 9 + kc) * 64 + q4 * 16 + (b & 15);
        unsigned int u = ((unsigned int)(unsigned short)f2bf(sm.m.t3row[ke + 1]) << 16)
                       | (unsigned short)f2bf(sm.m.t3row[ke]);
        cstoreu(t3u + d * 4 + ((ke & 7) >> 1), u);
      }
      signalflag(&flagsM[p * 128 + b], 1);
    }

    // ================= Stage C: contraction, h = blk =================
    {
      waitflags(flagsM + p * 128, 128, 1);
      // stage full t3aug (frag-major) into LDS via coherent loads
      for (int i = tid; i < B * KA / 2; i += 512)
        ((unsigned int*)sm.t3s)[i] = cloadu(t3u + i);
      __syncthreads();
      for (int m = 0; m < 8; m++) {
        short8 afr[9];
#pragma unroll
        for (int kc = 0; kc < 9; kc++)
          afr[kc] = *(const short8*)(sm.t3s + (size_t)((m * 9 + kc) * 64 + lane) * 8);
        f32x4 acc0 = {0.f, 0.f, 0.f, 0.f}, acc1 = {0.f, 0.f, 0.f, 0.f};
#pragma unroll
        for (int kc = 0; kc < 9; kc++) {
          acc0 = MFMA16(afr[kc], bfr[0][kc], acc0);
          if (nts > 1) acc1 = MFMA16(afr[kc], bfr[1][kc], acc1);
        }
        float part[4];
#pragma unroll
        for (int r = 0; r < 4; r++) {
          int row = m * 16 + q * 4 + r;
          float pv = acc0[r] * dX[(size_t)row * CP + nt0 * 16 + lm];
          if (nts > 1) pv += acc1[r] * dX[(size_t)row * CP + (nt0 + 1) * 16 + lm];
          part[r] = pv;
        }
#pragma unroll
        for (int r = 0; r < 4; r++) {
          part[r] += __shfl_xor(part[r], 1);
          part[r] += __shfl_xor(part[r], 2);
          part[r] += __shfl_xor(part[r], 4);
          part[r] += __shfl_xor(part[r], 8);
        }
        if (lm == 0) {
#pragma unroll
          for (int r = 0; r < 4; r++) red4[wave][m * 16 + q * 4 + r] = part[r];
        }
      }
      __syncthreads();
      if (tid < 128) {
        int row = tid;
        float s = 0.f;
#pragma unroll
        for (int w = 0; w < 8; w++) s += red4[w][row];
        float zo = zcol[row] + scale * s;
        if (pm) zcol[row] = zo;
        if (p == NPH - 1) z[(size_t)row * H + blk] = zo;
        short hi = f2bf(zo);
        short lo = f2bf(zo - bf2f(hi));
        cstoreu(Xu + row * H + blk,
                ((unsigned int)(unsigned short)hi << 16) | (unsigned short)lo);
      }
      signalflag(&flagsC[p * 256 + blk], 1);
    }
  }
}

// ---------------------------------------------------------------------------
// Kernel 6: output heads
// ---------------------------------------------------------------------------
__global__ __launch_bounds__(256) void k_final(const float* __restrict__ z,
    const float* __restrict__ yW1, const float* __restrict__ yb1,
    const float* __restrict__ yW2, const float* __restrict__ yb2,
    const float* __restrict__ zW1, const float* __restrict__ zb1,
    const float* __restrict__ zW2, const float* __restrict__ zb2,
    float* __restrict__ out) {
  __shared__ float ht[H];
  __shared__ float ry[128];
  __shared__ float rz[H];
  int b = blockIdx.x, tid = threadIdx.x;
  ht[tid] = z[(size_t)b * H + tid];
  __syncthreads();
  if (tid < 128) {
    float s = yb1[tid];
    for (int k = 0; k < H; k++) s += ht[k] * yW1[k * 128 + tid];
    ry[tid] = fmaxf(s, 0.f);
  }
  {
    float s = zb1[tid];
    for (int k = 0; k < H; k++) s += ht[k] * zW1[k * H + tid];
    rz[tid] = fmaxf(s, 0.f);
  }
  __syncthreads();
  if (tid < 64) {
    float sv = ry[tid] * yW2[tid] + ry[tid + 64] * yW2[tid + 64];
    for (int off = 32; off > 0; off >>= 1) sv += __shfl_down(sv, off);
    if (tid == 0) out[b] = sv + yb2[0];
  }
  if (tid < D) {
    float s = zb2[tid];
    for (int k = 0; k < H; k++) s += rz[k] * zW2[k * D + tid];
    out[B + b * D + tid] = s;
  }
  out[B + B * D + (size_t)b * H + tid] = ht[tid];
}

// ---------------------------------------------------------------------------
extern "C" void kernel_launch(void* const* d_in, const int* in_sizes, int n_in,
                              void* d_out, int out_size, void* d_ws, size_t ws_size,
                              hipStream_t stream) {
  const float* x   = (const float*)d_in[0];
  const float* hW1 = (const float*)d_in[1];
  const float* hb1 = (const float*)d_in[2];
  const float* hW2 = (const float*)d_in[3];
  const float* hb2 = (const float*)d_in[4];
  const float* fW1 = (const float*)d_in[5];
  const float* fb1 = (const float*)d_in[6];
  const float* g1  = (const float*)d_in[7];
  const float* be1 = (const float*)d_in[8];
  const float* fW2 = (const float*)d_in[9];
  const float* fb2 = (const float*)d_in[10];
  const float* g2  = (const float*)d_in[11];
  const float* be2 = (const float*)d_in[12];
  const float* fW3 = (const float*)d_in[13];
  const float* fb3 = (const float*)d_in[14];
  const float* fW4 = (const float*)d_in[15];
  const float* fb4 = (const float*)d_in[16];
  const float* yW1 = (const float*)d_in[17];
  const float* yb1 = (const float*)d_in[18];
  const float* yW2 = (const float*)d_in[19];
  const float* yb2 = (const float*)d_in[20];
  const float* zW1 = (const float*)d_in[21];
  const float* zb1 = (const float*)d_in[22];
  const float* zW2 = (const float*)d_in[23];
  const float* zb2 = (const float*)d_in[24];
  const float* sg  = (const float*)d_in[25];
  const float* sb  = (const float*)d_in[26];

  float* ws     = (float*)d_ws;
  float* dknot  = ws;                              // 1,935,360 f
  float* dmid   = dknot + (size_t)NSEG * B * CP;   // 1,935,360 f
  float* z      = dmid + (size_t)NSEG * B * CP;    // 32,768 f
  unsigned int* Xu = (unsigned int*)(z + B * H);   // 32,768 u
  unsigned int* t3u = Xu + B * H;                  // 18,432 u
  int* flagsM   = (int*)(t3u + B * KA / 2);        // 16,128 i
  int* flagsC   = flagsM + NPH * 128;              // 32,256 i
  short* w1b    = (short*)(flagsC + NPH * 256);    // 262,144 s
  short* w2b    = w1b + H * WMH;                   // 262,144 s
  short* w3b    = w2b + H * WMH;                   // 65,536 s
  short* W4T    = w3b + H * H;                     // 17,694,720 s
  float* y      = (float*)W4T;                     // temp alias (dead before W4T built)

  hipLaunchKernelGGL(k_logsig, dim3(B), dim3(256), 0, stream, x, sg, sb, y);
  hipLaunchKernelGGL(k_spline, dim3(B), dim3(256), 0, stream, y, dknot, dmid);
  hipLaunchKernelGGL(k_h0,     dim3(B), dim3(256), 0, stream, x, hW1, hb1, hW2, hb2, z, Xu);
  hipLaunchKernelGGL(k_prep_t,   dim3(928, 4), dim3(256), 0, stream, fW4, W4T);
  hipLaunchKernelGGL(k_prep_pad, dim3(9728),   dim3(256), 0, stream, fb4, W4T);
  hipLaunchKernelGGL(k_prep_w,   dim3(1024),   dim3(256), 0, stream, fW1, w1b, 262144);
  hipLaunchKernelGGL(k_prep_w,   dim3(1024),   dim3(256), 0, stream, fW2, w2b, 262144);
  hipLaunchKernelGGL(k_prep_w,   dim3(256),    dim3(256), 0, stream, fW3, w3b, 65536);
  hipLaunchKernelGGL(k_prep_t3pad, dim3(1), dim3(128), 0, stream, (short*)t3u);
  hipLaunchKernelGGL(k_prep_zero, dim3(189), dim3(256), 0, stream, flagsM, NPH * 384);

  void* args[] = {
    (void*)&w1b, (void*)&fb1, (void*)&g1, (void*)&be1,
    (void*)&w2b, (void*)&fb2, (void*)&g2, (void*)&be2,
    (void*)&w3b, (void*)&fb3, (void*)&W4T,
    (void*)&dknot, (void*)&dmid,
    (void*)&z, (void*)&Xu, (void*)&t3u,
    (void*)&flagsM, (void*)&flagsC
  };
  hipLaunchCooperativeKernel((const void*)k_scan, dim3(256), dim3(512), args, 0, stream);

  hipLaunchKernelGGL(k_final, dim3(B), dim3(256), 0, stream, z,
                     yW1, yb1, yW2, yb2, zW1, zb1, zW2, zb2, (float*)d_out);
}

// Round 7
// 7015.231 us; speedup vs baseline: 2.7997x; 1.0906x over previous
//
#include <hip/hip_runtime.h>

#define B 128
#define N 64
#define D 20
#define H 256
#define WMH 1024
#define CAUG 21
#define SIG 231
#define C 232
#define CP 240          // padded C
#define KA 288          // augmented K (256 + bias row + pad)
#define NSEG 63
#define NPH 126
#define HSTEP (1.0f/63.0f)
#define EPS 1e-5f

typedef __attribute__((ext_vector_type(8))) short short8;
typedef __attribute__((ext_vector_type(4))) float f32x4;
typedef __attribute__((ext_vector_type(4))) unsigned int uint4v;

__device__ inline short f2bf(float f) {
  unsigned int u = __float_as_uint(f);
  unsigned int r = (u + 0x7fffu + ((u >> 16) & 1u)) >> 16;
  return (short)r;
}
__device__ inline float bf2f(short h) {
  return __uint_as_float(((unsigned int)(unsigned short)h) << 16);
}
#define MFMA16(a, b, c) __builtin_amdgcn_mfma_f32_16x16x32_bf16((a), (b), (c), 0, 0, 0)

// --- relaxed agent-scope (device coherence point) accesses: no cache maint.
__device__ inline unsigned int cloadu(const unsigned int* p) {
  return __hip_atomic_load(p, __ATOMIC_RELAXED, __HIP_MEMORY_SCOPE_AGENT);
}
__device__ inline void cstoreu(unsigned int* p, unsigned int v) {
  __hip_atomic_store(p, v, __ATOMIC_RELAXED, __HIP_MEMORY_SCOPE_AGENT);
}
__device__ inline float cloadf(const float* p) {
  return __hip_atomic_load(p, __ATOMIC_RELAXED, __HIP_MEMORY_SCOPE_AGENT);
}
__device__ inline void cstoref(float* p, float v) {
  __hip_atomic_store(p, v, __ATOMIC_RELAXED, __HIP_MEMORY_SCOPE_AGENT);
}
__device__ inline int cloadi(const int* p) {
  return __hip_atomic_load(p, __ATOMIC_RELAXED, __HIP_MEMORY_SCOPE_AGENT);
}
__device__ inline void cstorei(int* p, int v) {
  __hip_atomic_store(p, v, __ATOMIC_RELAXED, __HIP_MEMORY_SCOPE_AGENT);
}

// R5-proven fabric: per-producer flag slots (padded to 64B), monotonic values.
__device__ inline void waitslots(const int* f, int n, int v) {
  for (int i = threadIdx.x; i < n; i += blockDim.x) {
    if (cloadi(f + i * 16) >= v) continue;
    do { __builtin_amdgcn_s_sleep(1); } while (cloadi(f + i * 16) < v);
  }
  __builtin_amdgcn_fence(__ATOMIC_ACQUIRE, "workgroup");   // s_waitcnt only
  __syncthreads();
}
__device__ inline void sigslot(int* f, int v) {
  __builtin_amdgcn_fence(__ATOMIC_RELEASE, "workgroup");   // vmcnt drain only
  __syncthreads();
  if (threadIdx.x == 0) cstorei(f, v);
}

// ---------------------------------------------------------------------------
// Kernel 1: depth-2 log-signature + LayerNorm -> y (B,N,C)
// ---------------------------------------------------------------------------
__global__ __launch_bounds__(256) void k_logsig(const float* __restrict__ x,
                                                const float* __restrict__ sg,
                                                const float* __restrict__ sb,
                                                float* __restrict__ y) {
  __shared__ float yb[N][C];
  int b = blockIdx.x, tid = threadIdx.x;
  for (int ii = tid; ii < N * CAUG; ii += 256) {
    int n = ii / CAUG, j = ii % CAUG;
    float v = (j == 0) ? (n * (1.0f / 63.0f)) : x[(b * N + n) * D + (j - 1)];
    yb[n][1 + j] = v;
  }
  __syncthreads();
  if (tid < 210) {
    int i = 0, rem = tid;
    while (rem >= (CAUG - 1) - i) { rem -= (CAUG - 1) - i; i++; }
    int j = i + 1 + rem;
    float acc = 0.f, pi_prev = 0.f, pj_prev = 0.f;
    for (int n = 0; n < N; n++) {
      float pi = yb[n][1 + i], pj = yb[n][1 + j];
      float di = pi - pi_prev, dj = pj - pj_prev;
      acc += 0.5f * (pi_prev * dj - di * pj_prev);
      yb[n][1 + CAUG + tid] = acc;
      pi_prev = pi; pj_prev = pj;
    }
  }
  __syncthreads();
  int w = tid >> 6, l = tid & 63;
  for (int n = w; n < N; n += 4) {
    float s1 = 0.f, s2 = 0.f;
    for (int s = l; s < SIG; s += 64) { float v = yb[n][1 + s]; s1 += v; s2 += v * v; }
    for (int off = 32; off > 0; off >>= 1) { s1 += __shfl_down(s1, off); s2 += __shfl_down(s2, off); }
    s1 = __shfl(s1, 0); s2 = __shfl(s2, 0);
    float mean = s1 * (1.0f / SIG);
    float var  = s2 * (1.0f / SIG) - mean * mean;
    float rs = rsqrtf(var + EPS);
    float* yrow = y + ((size_t)b * N + n) * C;
    if (l == 0) yrow[0] = n * (1.0f / 63.0f);
    for (int s = l; s < SIG; s += 64)
      yrow[1 + s] = (yb[n][1 + s] - mean) * rs * sg[s] + sb[s];
  }
}

// ---------------------------------------------------------------------------
// Kernel 2: natural cubic spline -> d_knot, d_mid (NSEG, B, CP) zero-padded
// ---------------------------------------------------------------------------
__global__ __launch_bounds__(256) void k_spline(const float* __restrict__ y,
                                                float* __restrict__ dknot,
                                                float* __restrict__ dmid) {
  __shared__ float yb[N * C];
  __shared__ float cp_s[62], id_s[62];
  int b = blockIdx.x, tid = threadIdx.x;
  for (int ii = tid; ii < N * C; ii += 256) yb[ii] = y[(size_t)b * N * C + ii];
  if (tid == 0) {
    const float a = HSTEP / 6.f, bb = 2.f * HSTEP / 3.f;
    float id0 = 1.f / bb; id_s[0] = id0; cp_s[0] = a * id0;
    for (int j = 1; j < 62; j++) {
      float den = bb - a * cp_s[j - 1];
      float idj = 1.f / den; id_s[j] = idj; cp_s[j] = a * idj;
    }
  }
  __syncthreads();
  int c = tid;
  if (c >= 232 && c < CP) {
    for (int n = 0; n < NSEG; n++) {
      dknot[((size_t)n * B + b) * CP + c] = 0.f;
      dmid [((size_t)n * B + b) * CP + c] = 0.f;
    }
  } else if (c < 232) {
    const float a = HSTEP / 6.f;
    float dp[62];
    dp[0] = (yb[2 * C + c] - 2.f * yb[1 * C + c] + yb[0 * C + c]) * 63.0f * id_s[0];
#pragma unroll
    for (int j = 1; j < 62; j++) {
      float rj = (yb[(j + 2) * C + c] - 2.f * yb[(j + 1) * C + c] + yb[j * C + c]) * 63.0f;
      dp[j] = (rj - a * dp[j - 1]) * id_s[j];
    }
#pragma unroll
    for (int j = 60; j >= 0; j--) dp[j] -= cp_s[j] * dp[j + 1];
#pragma unroll
    for (int n = 0; n < NSEG; n++) {
      float Mn  = (n == 0)  ? 0.f : dp[n - 1];
      float Mn1 = (n == 62) ? 0.f : dp[n];
      float dy = (yb[(n + 1) * C + c] - yb[n * C + c]) * 63.0f;
      dknot[((size_t)n * B + b) * CP + c] = dy - (HSTEP / 6.f)  * (2.f * Mn + Mn1);
      dmid [((size_t)n * B + b) * CP + c] = dy + (HSTEP / 24.f) * (Mn - Mn1);
    }
  }
}

// ---------------------------------------------------------------------------
// Kernel 3: initial hidden state -> z (f32) and Xu (packed hi|lo bf16)
// ---------------------------------------------------------------------------
__global__ __launch_bounds__(256) void k_h0(const float* __restrict__ x,
                                            const float* __restrict__ hW1,
                                            const float* __restrict__ hb1,
                                            const float* __restrict__ hW2,
                                            const float* __restrict__ hb2,
                                            float* __restrict__ z,
                                            unsigned int* __restrict__ Xu) {
  __shared__ float r[H];
  int b = blockIdx.x, tid = threadIdx.x;
  float s = hb1[tid];
#pragma unroll
  for (int d = 0; d < D; d++) s += x[(size_t)(b * N) * D + d] * hW1[d * H + tid];
  r[tid] = fmaxf(s, 0.f);
  __syncthreads();
  float s2 = hb2[tid];
  for (int k = 0; k < H; k++) s2 += r[k] * hW2[k * H + tid];
  z[b * H + tid] = s2;
  short hi = f2bf(s2);
  short lo = f2bf(s2 - bf2f(hi));
  Xu[b * H + tid] = ((unsigned int)(unsigned short)hi << 16) | (unsigned short)lo;
}

// ---------------------------------------------------------------------------
// Prep: transpose fW4 (256 x 59392) f32 -> W4T [h*240+c][288] bf16
// ---------------------------------------------------------------------------
__global__ __launch_bounds__(256) void k_prep_t(const float* __restrict__ fW4,
                                                short* __restrict__ W4T) {
  __shared__ float tile[64][65];
  int m0 = blockIdx.x * 64, k0 = blockIdx.y * 64;
  int lane = threadIdx.x & 63, wr = threadIdx.x >> 6;
#pragma unroll
  for (int j = 0; j < 16; j++) {
    int kk = wr * 16 + j;
    tile[kk][lane] = fW4[(size_t)(k0 + kk) * 59392 + m0 + lane];
  }
  __syncthreads();
#pragma unroll
  for (int j = 0; j < 16; j++) {
    int mloc = wr * 16 + j;
    int m = m0 + mloc;
    int hh = m / 232, cc = m - hh * 232;
    W4T[((size_t)hh * CP + cc) * KA + k0 + lane] = f2bf(tile[lane][mloc]);
  }
}

// Prep: fill k'=256 (bias), k'=257..287 zeros, and c>=232 zero rows of W4T
__global__ __launch_bounds__(256) void k_prep_pad(const float* __restrict__ fb4,
                                                  short* __restrict__ W4T) {
  int idx = blockIdx.x * 256 + threadIdx.x;
  const int partA = 61440 * 32;
  if (idx < partA) {
    int row = idx >> 5, j = idx & 31;
    int hh = row / CP, cc = row - hh * CP;
    short v = 0;
    if (j == 0 && cc < 232) v = f2bf(fb4[hh * 232 + cc]);
    W4T[(size_t)row * KA + 256 + j] = v;
  } else {
    int t = idx - partA;
    int k = t & 255; t >>= 8;
    int cc = 232 + (t & 7); int hh = t >> 3;
    W4T[((size_t)hh * CP + cc) * KA + k] = 0;
  }
}

// Prep: tiled transpose f32 (K x Nn) -> bf16 out[n][k]
__global__ __launch_bounds__(256) void k_prep_wt(const float* __restrict__ in,
                                                 short* __restrict__ out,
                                                 int K, int Nn) {
  __shared__ float tile[64][65];
  int n0 = blockIdx.x * 64, k0 = blockIdx.y * 64;
  int lane = threadIdx.x & 63, wr = threadIdx.x >> 6;
#pragma unroll
  for (int j = 0; j < 16; j++) {
    int kk = wr * 16 + j;
    tile[kk][lane] = in[(size_t)(k0 + kk) * Nn + n0 + lane];
  }
  __syncthreads();
#pragma unroll
  for (int j = 0; j < 16; j++) {
    int nl = wr * 16 + j;
    out[(size_t)(n0 + nl) * K + k0 + lane] = f2bf(tile[lane][nl]);
  }
}

// Prep: static part of frag-major t3aug (k'=256 bias=1, 257..287 = 0)
__global__ __launch_bounds__(128) void k_prep_t3pad(short* __restrict__ t3aug) {
  int r = threadIdx.x;
  if (r < 128) {
    int base = ((r >> 4) * 9 + 8) * 64 + (r & 15);
#pragma unroll
    for (int q = 0; q < 4; q++)
#pragma unroll
      for (int j = 0; j < 8; j++)
        t3aug[(size_t)(base + q * 16) * 8 + j] = (q == 0 && j == 0) ? (short)0x3F80 : (short)0;
  }
}

// Prep: zero int region
__global__ __launch_bounds__(256) void k_prep_zero(int* __restrict__ p, int n) {
  int i = blockIdx.x * 256 + threadIdx.x;
  if (i < n) p[i] = 0;
}

// ---------------------------------------------------------------------------
// Persistent scan: 256 blocks x 512 threads, per-slot flag sync (R5 fabric).
// S1 (blk<64):  T1 = X@W1+fb1 (16 cols/blk, w1 slice in LDS)
// S2 (blk<128): T2 = relu(LN1(T1))@W2+fb2 — LN stats block-local from the
//               values the block loads anyway (no cross-block atomics)
// S3 (blk<128): t3 = relu(relu(LN2(T2))@W3+fb3) -> frag-major packed bf16
// S4 (all):     z += scale*(t3 @ W4[h]).dX  (W4 slice in registers)
// ---------------------------------------------------------------------------
__global__ __launch_bounds__(512, 1) void k_scan(
    const short* __restrict__ W1T, const float* __restrict__ fb1,
    const float* __restrict__ g1,  const float* __restrict__ be1,
    const short* __restrict__ W2T, const float* __restrict__ fb2,
    const float* __restrict__ g2,  const float* __restrict__ be2,
    const short* __restrict__ W3T, const float* __restrict__ fb3,
    const short* __restrict__ W4T,
    const float* __restrict__ dknot, const float* __restrict__ dmid,
    float* __restrict__ z, unsigned int* __restrict__ Xu,
    unsigned int* __restrict__ t3u,
    float* __restrict__ T1, float* __restrict__ T2,
    int* __restrict__ flags) {
  const int blk = blockIdx.x;
  const int tid = threadIdx.x;
  const int wave = tid >> 6, lane = tid & 63;
  const int lm = lane & 15, q = lane >> 4;

  __shared__ short w1s[8 * 64 * 8];      //  8 KB
  __shared__ short w2s[32 * 64 * 8];     // 32 KB
  __shared__ short w3s[8 * 64 * 8];      //  8 KB
  __shared__ short t3s[B * KA];          // 72 KB
  __shared__ float red2[8][256];         //  8 KB
  __shared__ float red4[8][128];         //  4 KB
  __shared__ float zcol[128];

  int* fM1 = flags;              // 64 slots (x16)
  int* fM2 = flags + 1024;       // 128 slots
  int* fM3 = flags + 3072;       // 128 slots
  int* fC  = flags + 5120;       // 256 slots

  // persistent B-fragments: this block's W4 slice in registers
  const int nts = (wave < 7) ? 2 : 1;
  const int nt0 = wave * 2;
  short8 bfr[2][9];
  for (int t = 0; t < nts; t++) {
    const short* wp = W4T + ((size_t)blk * CP + (nt0 + t) * 16 + lm) * KA + q * 8;
#pragma unroll
    for (int kc = 0; kc < 9; kc++)
      bfr[t][kc] = *(const short8*)(wp + kc * 32);
  }
  // one-time LDS weight residency (frag-major)
  if (blk < 64) {
    int kc = tid >> 6;
    *(short8*)(w1s + (size_t)tid * 8) =
        *(const short8*)(W1T + (size_t)(blk * 16 + lm) * H + kc * 32 + q * 8);
  }
  if (blk < 128) {
    int n = blk & 15;
#pragma unroll
    for (int r = 0; r < 4; r++) {
      int u = tid + r * 512;
      int wk = u >> 6, ln = u & 63, lmi = ln & 15, qi = ln >> 4;
      int wv = wk >> 2, kc = wk & 3;
      *(short8*)(w2s + (size_t)u * 8) =
          *(const short8*)(W2T + (size_t)(n * 16 + lmi) * WMH + wv * 128 + kc * 32 + qi * 8);
    }
    int wv = tid >> 6;
    *(short8*)(w3s + (size_t)tid * 8) =
        *(const short8*)(W3T + (size_t)(n * 16 + lm) * H + wv * 32 + q * 8);
  }
  if (tid < 128) zcol[tid] = z[(size_t)tid * H + blk];
  __syncthreads();

  for (int p = 0; p < NPH; p++) {
    const int seg = p >> 1, pm = p & 1;
    const float* dX = (pm ? dmid : dknot) + (size_t)seg * B * CP;
    const float scale = pm ? HSTEP : 0.5f * HSTEP;

    // ---- S1: T1 = X @ W1 + fb1 ----
    if (blk < 64) {
      if (p) waitslots(fC, 256, p);
      const int n0 = blk * 16;
      const int arow = wave * 16 + lm;
      const unsigned int* xp = Xu + arow * H;
      f32x4 acc = {0.f, 0.f, 0.f, 0.f};
#pragma unroll
      for (int kc = 0; kc < 8; kc++) {
        short8 bw = *(const short8*)(w1s + (size_t)(kc * 64 + lane) * 8);
        short8 ah, al;
#pragma unroll
        for (int j = 0; j < 8; j++) {
          unsigned int u = cloadu(xp + kc * 32 + q * 8 + j);
          ah[j] = (short)(u >> 16);
          al[j] = (short)(u & 0xffffu);
        }
        acc = MFMA16(ah, bw, acc);
        acc = MFMA16(al, bw, acc);
      }
      float fb = fb1[n0 + lm];
#pragma unroll
      for (int r = 0; r < 4; r++) {
        int row = wave * 16 + q * 4 + r;
        cstoref(T1 + (size_t)row * WMH + n0 + lm, acc[r] + fb);
      }
      sigslot(fM1 + blk * 16, p + 1);
    }

    // ---- S2: T2 = relu(LN1(T1)) @ W2 + fb2, block-local stats ----
    if (blk < 128) {
      waitslots(fM1, 64, p + 1);
      const int m = blk >> 4, n = blk & 15;
      const int row = m * 16 + lm;
      float tv[32];
      float s = 0.f, ss = 0.f;
#pragma unroll
      for (int kc = 0; kc < 4; kc++) {
        int kg = wave * 128 + kc * 32 + q * 8;
        const float* tp = T1 + (size_t)row * WMH + kg;
#pragma unroll
        for (int j = 0; j < 8; j++) {
          float v = cloadf(tp + j);
          tv[kc * 8 + j] = v;
          s += v; ss += v * v;
        }
      }
      // reduce over quads (same lm across q): lane xor 16, 32
      s += __shfl_xor(s, 16); ss += __shfl_xor(ss, 16);
      s += __shfl_xor(s, 32); ss += __shfl_xor(ss, 32);
      if (q == 0) { red2[wave][lm] = s; red2[wave][lm + 16] = ss; }
      __syncthreads();
      float S = 0.f, SS = 0.f;
#pragma unroll
      for (int w = 0; w < 8; w++) { S += red2[w][lm]; SS += red2[w][lm + 16]; }
      float mean = S * (1.f / WMH);
      float var  = SS * (1.f / WMH) - mean * mean;
      float rsv  = rsqrtf(var + EPS);
      __syncthreads();   // red2 reused for MFMA partials below
      f32x4 acc = {0.f, 0.f, 0.f, 0.f};
#pragma unroll
      for (int kc = 0; kc < 4; kc++) {
        int kg = wave * 128 + kc * 32 + q * 8;
        short8 ah, al;
#pragma unroll
        for (int j = 0; j < 8; j++) {
          float a = fmaxf((tv[kc * 8 + j] - mean) * rsv * g1[kg + j] + be1[kg + j], 0.f);
          short hi = f2bf(a);
          ah[j] = hi;
          al[j] = f2bf(a - bf2f(hi));
        }
        short8 bw = *(const short8*)(w2s + (size_t)((wave * 4 + kc) * 64 + lane) * 8);
        acc = MFMA16(ah, bw, acc);
        acc = MFMA16(al, bw, acc);
      }
#pragma unroll
      for (int r = 0; r < 4; r++) red2[wave][(q * 4 + r) * 16 + lm] = acc[r];
      __syncthreads();
      if (tid < 256) {
        int ri = tid >> 4, ci = tid & 15;
        float v = fb2[n * 16 + ci];
#pragma unroll
        for (int w = 0; w < 8; w++) v += red2[w][tid];
        cstoref(T2 + (size_t)(m * 16 + ri) * H + n * 16 + ci, v);
      }
      sigslot(fM2 + blk * 16, p + 1);
    }

    // ---- S3: t3 = relu(relu(LN2(T2)) @ W3 + fb3), block-local stats ----
    if (blk < 128) {
      waitslots(fM2, 128, p + 1);
      const int m = blk >> 4, n = blk & 15;
      const int row = m * 16 + lm;
      int kg = wave * 32 + q * 8;
      const float* tp = T2 + (size_t)row * H + kg;
      float tv[8];
      float s = 0.f, ss = 0.f;
#pragma unroll
      for (int j = 0; j < 8; j++) {
        float v = cloadf(tp + j);
        tv[j] = v;
        s += v; ss += v * v;
      }
      s += __shfl_xor(s, 16); ss += __shfl_xor(ss, 16);
      s += __shfl_xor(s, 32); ss += __shfl_xor(ss, 32);
      if (q == 0) { red2[wave][lm] = s; red2[wave][lm + 16] = ss; }
      __syncthreads();
      float S = 0.f, SS = 0.f;
#pragma unroll
      for (int w = 0; w < 8; w++) { S += red2[w][lm]; SS += red2[w][lm + 16]; }
      float mean = S * (1.f / H);
      float var  = SS * (1.f / H) - mean * mean;
      float rsv  = rsqrtf(var + EPS);
      __syncthreads();
      short8 ah, al;
#pragma unroll
      for (int j = 0; j < 8; j++) {
        float a = fmaxf((tv[j] - mean) * rsv * g2[kg + j] + be2[kg + j], 0.f);
        short hi = f2bf(a);
        ah[j] = hi;
        al[j] = f2bf(a - bf2f(hi));
      }
      short8 bw = *(const short8*)(w3s + (size_t)(wave * 64 + lane) * 8);
      f32x4 acc = {0.f, 0.f, 0.f, 0.f};
      acc = MFMA16(ah, bw, acc);
      acc = MFMA16(al, bw, acc);
#pragma unroll
      for (int r = 0; r < 4; r++) red2[wave][(q * 4 + r) * 16 + lm] = acc[r];
      __syncthreads();
      if (tid < 256) {
        int ri = tid >> 4, ci = tid & 15;
        float v = fb3[n * 16 + ci];
#pragma unroll
        for (int w = 0; w < 8; w++) v += red2[w][tid];
        v = fmaxf(v, 0.f);
        float vo = __shfl_xor(v, 1);
        if ((ci & 1) == 0) {
          int kglob = n * 16 + ci;
          int d = (m * 9 + (kglob >> 5)) * 64 + ((kglob >> 3) & 3) * 16 + ri;
          unsigned int u = ((unsigned int)(unsigned short)f2bf(vo) << 16)
                         | (unsigned short)f2bf(v);
          cstoreu(t3u + d * 4 + ((kglob & 7) >> 1), u);
        }
      }
      sigslot(fM3 + blk * 16, p + 1);
    }

    // ---- S4: all 256 blocks, h = blk ----
    {
      waitslots(fM3, 128, p + 1);
#pragma unroll
      for (int j = 0; j < 9; j++) {
        int bd = j * 2048 + tid * 4;
        uint4v uv;
        uv.x = cloadu(t3u + bd);
        uv.y = cloadu(t3u + bd + 1);
        uv.z = cloadu(t3u + bd + 2);
        uv.w = cloadu(t3u + bd + 3);
        *(uint4v*)(t3s + (size_t)bd * 2) = uv;
      }
      __syncthreads();
      for (int m = 0; m < 8; m++) {
        short8 afr[9];
#pragma unroll
        for (int kc = 0; kc < 9; kc++)
          afr[kc] = *(const short8*)(t3s + (size_t)((m * 9 + kc) * 64 + lane) * 8);
        f32x4 acc0 = {0.f, 0.f, 0.f, 0.f}, acc1 = {0.f, 0.f, 0.f, 0.f};
#pragma unroll
        for (int kc = 0; kc < 9; kc++) {
          acc0 = MFMA16(afr[kc], bfr[0][kc], acc0);
          if (nts > 1) acc1 = MFMA16(afr[kc], bfr[1][kc], acc1);
        }
        float part[4];
#pragma unroll
        for (int r = 0; r < 4; r++) {
          int row = m * 16 + q * 4 + r;
          float pv = acc0[r] * dX[(size_t)row * CP + nt0 * 16 + lm];
          if (nts > 1) pv += acc1[r] * dX[(size_t)row * CP + (nt0 + 1) * 16 + lm];
          part[r] = pv;
        }
#pragma unroll
        for (int r = 0; r < 4; r++) {
          part[r] += __shfl_xor(part[r], 1);
          part[r] += __shfl_xor(part[r], 2);
          part[r] += __shfl_xor(part[r], 4);
          part[r] += __shfl_xor(part[r], 8);
        }
        if (lm == 0) {
#pragma unroll
          for (int r = 0; r < 4; r++) red4[wave][m * 16 + q * 4 + r] = part[r];
        }
      }
      __syncthreads();
      if (tid < 128) {
        int row = tid;
        float s = 0.f;
#pragma unroll
        for (int w = 0; w < 8; w++) s += red4[w][row];
        float zo = zcol[row] + scale * s;
        if (pm) zcol[row] = zo;
        if (p == NPH - 1) z[(size_t)row * H + blk] = zo;
        short hi = f2bf(zo);
        short lo = f2bf(zo - bf2f(hi));
        cstoreu(Xu + row * H + blk,
                ((unsigned int)(unsigned short)hi << 16) | (unsigned short)lo);
      }
      sigslot(fC + blk * 16, p + 1);
    }
  }
}

// ---------------------------------------------------------------------------
// Kernel 6: output heads
// ---------------------------------------------------------------------------
__global__ __launch_bounds__(256) void k_final(const float* __restrict__ z,
    const float* __restrict__ yW1, const float* __restrict__ yb1,
    const float* __restrict__ yW2, const float* __restrict__ yb2,
    const float* __restrict__ zW1, const float* __restrict__ zb1,
    const float* __restrict__ zW2, const float* __restrict__ zb2,
    float* __restrict__ out) {
  __shared__ float ht[H];
  __shared__ float ry[128];
  __shared__ float rz[H];
  int b = blockIdx.x, tid = threadIdx.x;
  ht[tid] = z[(size_t)b * H + tid];
  __syncthreads();
  if (tid < 128) {
    float s = yb1[tid];
    for (int k = 0; k < H; k++) s += ht[k] * yW1[k * 128 + tid];
    ry[tid] = fmaxf(s, 0.f);
  }
  {
    float s = zb1[tid];
    for (int k = 0; k < H; k++) s += ht[k] * zW1[k * H + tid];
    rz[tid] = fmaxf(s, 0.f);
  }
  __syncthreads();
  if (tid < 64) {
    float sv = ry[tid] * yW2[tid] + ry[tid + 64] * yW2[tid + 64];
    for (int off = 32; off > 0; off >>= 1) sv += __shfl_down(sv, off);
    if (tid == 0) out[b] = sv + yb2[0];
  }
  if (tid < D) {
    float s = zb2[tid];
    for (int k = 0; k < H; k++) s += rz[k] * zW2[k * D + tid];
    out[B + b * D + tid] = s;
  }
  out[B + B * D + (size_t)b * H + tid] = ht[tid];
}

// ---------------------------------------------------------------------------
extern "C" void kernel_launch(void* const* d_in, const int* in_sizes, int n_in,
                              void* d_out, int out_size, void* d_ws, size_t ws_size,
                              hipStream_t stream) {
  const float* x   = (const float*)d_in[0];
  const float* hW1 = (const float*)d_in[1];
  const float* hb1 = (const float*)d_in[2];
  const float* hW2 = (const float*)d_in[3];
  const float* hb2 = (const float*)d_in[4];
  const float* fW1 = (const float*)d_in[5];
  const float* fb1 = (const float*)d_in[6];
  const float* g1  = (const float*)d_in[7];
  const float* be1 = (const float*)d_in[8];
  const float* fW2 = (const float*)d_in[9];
  const float* fb2 = (const float*)d_in[10];
  const float* g2  = (const float*)d_in[11];
  const float* be2 = (const float*)d_in[12];
  const float* fW3 = (const float*)d_in[13];
  const float* fb3 = (const float*)d_in[14];
  const float* fW4 = (const float*)d_in[15];
  const float* fb4 = (const float*)d_in[16];
  const float* yW1 = (const float*)d_in[17];
  const float* yb1 = (const float*)d_in[18];
  const float* yW2 = (const float*)d_in[19];
  const float* yb2 = (const float*)d_in[20];
  const float* zW1 = (const float*)d_in[21];
  const float* zb1 = (const float*)d_in[22];
  const float* zW2 = (const float*)d_in[23];
  const float* zb2 = (const float*)d_in[24];
  const float* sg  = (const float*)d_in[25];
  const float* sb  = (const float*)d_in[26];

  float* ws     = (float*)d_ws;
  float* dknot  = ws;                               // 1,935,360 f
  float* dmid   = dknot + (size_t)NSEG * B * CP;    // 1,935,360 f
  float* z      = dmid + (size_t)NSEG * B * CP;     // 32,768 f
  float* T1     = z + B * H;                        // 131,072 f
  float* T2     = T1 + B * WMH;                     // 32,768 f
  unsigned int* Xu = (unsigned int*)(T2 + B * H);   // 32,768 u
  unsigned int* t3u = Xu + B * H;                   // 18,432 u
  int* flags    = (int*)(t3u + B * KA / 2);         // 9,216 i
  short* w1T    = (short*)(flags + 9216);           // 262,144 s
  short* w2T    = w1T + H * WMH;                    // 262,144 s
  short* w3T    = w2T + H * WMH;                    // 65,536 s
  short* W4T    = w3T + H * H;                      // 17,694,720 s
  float* y      = (float*)W4T;                      // temp alias (dead before W4T built)

  hipLaunchKernelGGL(k_logsig, dim3(B), dim3(256), 0, stream, x, sg, sb, y);
  hipLaunchKernelGGL(k_spline, dim3(B), dim3(256), 0, stream, y, dknot, dmid);
  hipLaunchKernelGGL(k_h0,     dim3(B), dim3(256), 0, stream, x, hW1, hb1, hW2, hb2, z, Xu);
  hipLaunchKernelGGL(k_prep_t,   dim3(928, 4), dim3(256), 0, stream, fW4, W4T);
  hipLaunchKernelGGL(k_prep_pad, dim3(9728),   dim3(256), 0, stream, fb4, W4T);
  hipLaunchKernelGGL(k_prep_wt,  dim3(16, 4),  dim3(256), 0, stream, fW1, w1T, H, WMH);
  hipLaunchKernelGGL(k_prep_wt,  dim3(4, 16),  dim3(256), 0, stream, fW2, w2T, WMH, H);
  hipLaunchKernelGGL(k_prep_wt,  dim3(4, 4),   dim3(256), 0, stream, fW3, w3T, H, H);
  hipLaunchKernelGGL(k_prep_t3pad, dim3(1), dim3(128), 0, stream, (short*)t3u);
  hipLaunchKernelGGL(k_prep_zero, dim3(36), dim3(256), 0, stream, flags, 9216);

  void* args[] = {
    (void*)&w1T, (void*)&fb1, (void*)&g1, (void*)&be1,
    (void*)&w2T, (void*)&fb2, (void*)&g2, (void*)&be2,
    (void*)&w3T, (void*)&fb3, (void*)&W4T,
    (void*)&dknot, (void*)&dmid,
    (void*)&z, (void*)&Xu, (void*)&t3u,
    (void*)&T1, (void*)&T2, (void*)&flags
  };
  hipLaunchCooperativeKernel((const void*)k_scan, dim3(256), dim3(512), args, 0, stream);

  hipLaunchKernelGGL(k_final, dim3(B), dim3(256), 0, stream, z,
                     yW1, yb1, yW2, yb2, zW1, zb1, zW2, zb2, (float*)d_out);
}

// Round 8
// 4565.458 us; speedup vs baseline: 4.3020x; 1.5366x over previous
//
#include <hip/hip_runtime.h>

#define B 128
#define N 64
#define D 20
#define H 256
#define WMH 1024
#define CAUG 21
#define SIG 231
#define C 232
#define CP 240          // padded C
#define KA 288          // augmented K (256 + bias row + pad)
#define NSEG 63
#define NPH 126
#define HSTEP (1.0f/63.0f)
#define EPS 1e-5f

typedef __attribute__((ext_vector_type(8))) short short8;
typedef __attribute__((ext_vector_type(4))) float f32x4;
typedef __attribute__((ext_vector_type(4))) unsigned int uint4v;
typedef unsigned int uint;

__device__ inline short f2bf(float f) {
  uint u = __float_as_uint(f);
  uint r = (u + 0x7fffu + ((u >> 16) & 1u)) >> 16;
  return (short)r;
}
__device__ inline float bf2f(short h) {
  return __uint_as_float(((uint)(unsigned short)h) << 16);
}
#define MFMA16(a, b, c) __builtin_amdgcn_mfma_f32_16x16x32_bf16((a), (b), (c), 0, 0, 0)

// --- relaxed agent-scope scalar coherent ops (compiler-emitted, L2-bypassing)
__device__ inline uint cloadu(const uint* p) {
  return __hip_atomic_load(p, __ATOMIC_RELAXED, __HIP_MEMORY_SCOPE_AGENT);
}
__device__ inline void cstoreu(uint* p, uint v) {
  __hip_atomic_store(p, v, __ATOMIC_RELAXED, __HIP_MEMORY_SCOPE_AGENT);
}
__device__ inline void cstoref(float* p, float v) {
  __hip_atomic_store(p, v, __ATOMIC_RELAXED, __HIP_MEMORY_SCOPE_AGENT);
}
__device__ inline int cloadi(const int* p) {
  return __hip_atomic_load(p, __ATOMIC_RELAXED, __HIP_MEMORY_SCOPE_AGENT);
}
__device__ inline void cstorei(int* p, int v) {
  __hip_atomic_store(p, v, __ATOMIC_RELAXED, __HIP_MEMORY_SCOPE_AGENT);
}

// --- batched coherent vector loads (sc0 sc1 = read through to coherence point)
#define CLOAD8(r0,r1,r2,r3,r4,r5,r6,r7,addr)                                   \
  asm volatile("global_load_dwordx4 %0, %8, off sc0 sc1\n\t"                   \
               "global_load_dwordx4 %1, %8, off offset:16 sc0 sc1\n\t"         \
               "global_load_dwordx4 %2, %8, off offset:128 sc0 sc1\n\t"        \
               "global_load_dwordx4 %3, %8, off offset:144 sc0 sc1\n\t"        \
               "global_load_dwordx4 %4, %8, off offset:256 sc0 sc1\n\t"        \
               "global_load_dwordx4 %5, %8, off offset:272 sc0 sc1\n\t"        \
               "global_load_dwordx4 %6, %8, off offset:384 sc0 sc1\n\t"        \
               "global_load_dwordx4 %7, %8, off offset:400 sc0 sc1\n\t"        \
               "s_waitcnt vmcnt(0)"                                            \
               : "=&v"(r0), "=&v"(r1), "=&v"(r2), "=&v"(r3),                   \
                 "=&v"(r4), "=&v"(r5), "=&v"(r6), "=&v"(r7)                    \
               : "v"(addr)                                                     \
               : "memory")

#define CLOAD2(r0,r1,addr)                                                     \
  asm volatile("global_load_dwordx4 %0, %2, off sc0 sc1\n\t"                   \
               "global_load_dwordx4 %1, %2, off offset:16 sc0 sc1\n\t"         \
               "s_waitcnt vmcnt(0)"                                            \
               : "=&v"(r0), "=&v"(r1) : "v"(addr) : "memory")

#define CLOAD3A(r0,r1,r2,a0,a1,a2)                                             \
  asm volatile("global_load_dwordx4 %0, %3, off sc0 sc1\n\t"                   \
               "global_load_dwordx4 %1, %4, off sc0 sc1\n\t"                   \
               "global_load_dwordx4 %2, %5, off sc0 sc1\n\t"                   \
               "s_waitcnt vmcnt(0)"                                            \
               : "=&v"(r0), "=&v"(r1), "=&v"(r2)                               \
               : "v"(a0), "v"(a1), "v"(a2) : "memory")

// single-line flag wait: ONE polling thread per block
__device__ inline void waitflag(const int* f, int v) {
  if (threadIdx.x == 0) {
    while (cloadi(f) < v) __builtin_amdgcn_s_sleep(2);
  }
  __builtin_amdgcn_fence(__ATOMIC_ACQUIRE, "workgroup");   // s_waitcnt only
  __syncthreads();
}
// producers: returning fetch_add on counter line; last one publishes flag
__device__ inline void siggroup(int* c, int nprod, int* flag) {
  __builtin_amdgcn_fence(__ATOMIC_RELEASE, "workgroup");   // vmcnt drain only
  __syncthreads();
  if (threadIdx.x == 0) {
    int old = __hip_atomic_fetch_add(c, 1, __ATOMIC_RELAXED, __HIP_MEMORY_SCOPE_AGENT);
    if (old == nprod - 1) cstorei(flag, 1);
  }
}

__device__ inline void unpk(uint4v a, uint4v b, short8& ah, short8& al) {
#pragma unroll
  for (int e = 0; e < 4; e++) {
    ah[e]     = (short)(a[e] >> 16); al[e]     = (short)(a[e] & 0xffffu);
    ah[4 + e] = (short)(b[e] >> 16); al[4 + e] = (short)(b[e] & 0xffffu);
  }
}

// ---------------------------------------------------------------------------
// Kernel 1: depth-2 log-signature + LayerNorm -> y (B,N,C)
// ---------------------------------------------------------------------------
__global__ __launch_bounds__(256) void k_logsig(const float* __restrict__ x,
                                                const float* __restrict__ sg,
                                                const float* __restrict__ sb,
                                                float* __restrict__ y) {
  __shared__ float yb[N][C];
  int b = blockIdx.x, tid = threadIdx.x;
  for (int ii = tid; ii < N * CAUG; ii += 256) {
    int n = ii / CAUG, j = ii % CAUG;
    float v = (j == 0) ? (n * (1.0f / 63.0f)) : x[(b * N + n) * D + (j - 1)];
    yb[n][1 + j] = v;
  }
  __syncthreads();
  if (tid < 210) {
    int i = 0, rem = tid;
    while (rem >= (CAUG - 1) - i) { rem -= (CAUG - 1) - i; i++; }
    int j = i + 1 + rem;
    float acc = 0.f, pi_prev = 0.f, pj_prev = 0.f;
    for (int n = 0; n < N; n++) {
      float pi = yb[n][1 + i], pj = yb[n][1 + j];
      float di = pi - pi_prev, dj = pj - pj_prev;
      acc += 0.5f * (pi_prev * dj - di * pj_prev);
      yb[n][1 + CAUG + tid] = acc;
      pi_prev = pi; pj_prev = pj;
    }
  }
  __syncthreads();
  int w = tid >> 6, l = tid & 63;
  for (int n = w; n < N; n += 4) {
    float s1 = 0.f, s2 = 0.f;
    for (int s = l; s < SIG; s += 64) { float v = yb[n][1 + s]; s1 += v; s2 += v * v; }
    for (int off = 32; off > 0; off >>= 1) { s1 += __shfl_down(s1, off); s2 += __shfl_down(s2, off); }
    s1 = __shfl(s1, 0); s2 = __shfl(s2, 0);
    float mean = s1 * (1.0f / SIG);
    float var  = s2 * (1.0f / SIG) - mean * mean;
    float rs = rsqrtf(var + EPS);
    float* yrow = y + ((size_t)b * N + n) * C;
    if (l == 0) yrow[0] = n * (1.0f / 63.0f);
    for (int s = l; s < SIG; s += 64)
      yrow[1 + s] = (yb[n][1 + s] - mean) * rs * sg[s] + sb[s];
  }
}

// ---------------------------------------------------------------------------
// Kernel 2: natural cubic spline -> d_knot, d_mid (NSEG, B, CP) zero-padded
// ---------------------------------------------------------------------------
__global__ __launch_bounds__(256) void k_spline(const float* __restrict__ y,
                                                float* __restrict__ dknot,
                                                float* __restrict__ dmid) {
  __shared__ float yb[N * C];
  __shared__ float cp_s[62], id_s[62];
  int b = blockIdx.x, tid = threadIdx.x;
  for (int ii = tid; ii < N * C; ii += 256) yb[ii] = y[(size_t)b * N * C + ii];
  if (tid == 0) {
    const float a = HSTEP / 6.f, bb = 2.f * HSTEP / 3.f;
    float id0 = 1.f / bb; id_s[0] = id0; cp_s[0] = a * id0;
    for (int j = 1; j < 62; j++) {
      float den = bb - a * cp_s[j - 1];
      float idj = 1.f / den; id_s[j] = idj; cp_s[j] = a * idj;
    }
  }
  __syncthreads();
  int c = tid;
  if (c >= 232 && c < CP) {
    for (int n = 0; n < NSEG; n++) {
      dknot[((size_t)n * B + b) * CP + c] = 0.f;
      dmid [((size_t)n * B + b) * CP + c] = 0.f;
    }
  } else if (c < 232) {
    const float a = HSTEP / 6.f;
    float dp[62];
    dp[0] = (yb[2 * C + c] - 2.f * yb[1 * C + c] + yb[0 * C + c]) * 63.0f * id_s[0];
#pragma unroll
    for (int j = 1; j < 62; j++) {
      float rj = (yb[(j + 2) * C + c] - 2.f * yb[(j + 1) * C + c] + yb[j * C + c]) * 63.0f;
      dp[j] = (rj - a * dp[j - 1]) * id_s[j];
    }
#pragma unroll
    for (int j = 60; j >= 0; j--) dp[j] -= cp_s[j] * dp[j + 1];
#pragma unroll
    for (int n = 0; n < NSEG; n++) {
      float Mn  = (n == 0)  ? 0.f : dp[n - 1];
      float Mn1 = (n == 62) ? 0.f : dp[n];
      float dy = (yb[(n + 1) * C + c] - yb[n * C + c]) * 63.0f;
      dknot[((size_t)n * B + b) * CP + c] = dy - (HSTEP / 6.f)  * (2.f * Mn + Mn1);
      dmid [((size_t)n * B + b) * CP + c] = dy + (HSTEP / 24.f) * (Mn - Mn1);
    }
  }
}

// ---------------------------------------------------------------------------
// Kernel 3: initial hidden state -> z (f32) and Xu (packed hi|lo bf16)
// ---------------------------------------------------------------------------
__global__ __launch_bounds__(256) void k_h0(const float* __restrict__ x,
                                            const float* __restrict__ hW1,
                                            const float* __restrict__ hb1,
                                            const float* __restrict__ hW2,
                                            const float* __restrict__ hb2,
                                            float* __restrict__ z,
                                            uint* __restrict__ Xu) {
  __shared__ float r[H];
  int b = blockIdx.x, tid = threadIdx.x;
  float s = hb1[tid];
#pragma unroll
  for (int d = 0; d < D; d++) s += x[(size_t)(b * N) * D + d] * hW1[d * H + tid];
  r[tid] = fmaxf(s, 0.f);
  __syncthreads();
  float s2 = hb2[tid];
  for (int k = 0; k < H; k++) s2 += r[k] * hW2[k * H + tid];
  z[b * H + tid] = s2;
  short hi = f2bf(s2);
  short lo = f2bf(s2 - bf2f(hi));
  Xu[b * H + tid] = ((uint)(unsigned short)hi << 16) | (unsigned short)lo;
}

// ---------------------------------------------------------------------------
// Prep: transpose fW4 (256 x 59392) f32 -> W4T [h*240+c][288] bf16
// ---------------------------------------------------------------------------
__global__ __launch_bounds__(256) void k_prep_t(const float* __restrict__ fW4,
                                                short* __restrict__ W4T) {
  __shared__ float tile[64][65];
  int m0 = blockIdx.x * 64, k0 = blockIdx.y * 64;
  int lane = threadIdx.x & 63, wr = threadIdx.x >> 6;
#pragma unroll
  for (int j = 0; j < 16; j++) {
    int kk = wr * 16 + j;
    tile[kk][lane] = fW4[(size_t)(k0 + kk) * 59392 + m0 + lane];
  }
  __syncthreads();
#pragma unroll
  for (int j = 0; j < 16; j++) {
    int mloc = wr * 16 + j;
    int m = m0 + mloc;
    int hh = m / 232, cc = m - hh * 232;
    W4T[((size_t)hh * CP + cc) * KA + k0 + lane] = f2bf(tile[lane][mloc]);
  }
}

// Prep: fill k'=256 (bias), k'=257..287 zeros, and c>=232 zero rows of W4T
__global__ __launch_bounds__(256) void k_prep_pad(const float* __restrict__ fb4,
                                                  short* __restrict__ W4T) {
  int idx = blockIdx.x * 256 + threadIdx.x;
  const int partA = 61440 * 32;
  if (idx < partA) {
    int row = idx >> 5, j = idx & 31;
    int hh = row / CP, cc = row - hh * CP;
    short v = 0;
    if (j == 0 && cc < 232) v = f2bf(fb4[hh * 232 + cc]);
    W4T[(size_t)row * KA + 256 + j] = v;
  } else {
    int t = idx - partA;
    int k = t & 255; t >>= 8;
    int cc = 232 + (t & 7); int hh = t >> 3;
    W4T[((size_t)hh * CP + cc) * KA + k] = 0;
  }
}

// Prep: tiled transpose f32 (K x Nn) -> bf16 out[n][k]
__global__ __launch_bounds__(256) void k_prep_wt(const float* __restrict__ in,
                                                 short* __restrict__ out,
                                                 int K, int Nn) {
  __shared__ float tile[64][65];
  int n0 = blockIdx.x * 64, k0 = blockIdx.y * 64;
  int lane = threadIdx.x & 63, wr = threadIdx.x >> 6;
#pragma unroll
  for (int j = 0; j < 16; j++) {
    int kk = wr * 16 + j;
    tile[kk][lane] = in[(size_t)(k0 + kk) * Nn + n0 + lane];
  }
  __syncthreads();
#pragma unroll
  for (int j = 0; j < 16; j++) {
    int nl = wr * 16 + j;
    out[(size_t)(n0 + nl) * K + k0 + lane] = f2bf(tile[lane][nl]);
  }
}

// Prep: static part of frag-major t3aug (k'=256 bias=1, 257..287 = 0)
__global__ __launch_bounds__(128) void k_prep_t3pad(short* __restrict__ t3aug) {
  int r = threadIdx.x;
  if (r < 128) {
    int base = ((r >> 4) * 9 + 8) * 64 + (r & 15);
#pragma unroll
    for (int q = 0; q < 4; q++)
#pragma unroll
      for (int j = 0; j < 8; j++)
        t3aug[(size_t)(base + q * 16) * 8 + j] = (q == 0 && j == 0) ? (short)0x3F80 : (short)0;
  }
}

// Prep: zero int region
__global__ __launch_bounds__(256) void k_prep_zero(int* __restrict__ p, int n) {
  int i = blockIdx.x * 256 + threadIdx.x;
  if (i < n) p[i] = 0;
}

// ---------------------------------------------------------------------------
// Persistent scan: 256 blocks x 512 threads. Per phase:
// S1 (blk<128, (m,j)): T1[m-rows, j*64 cols] = X@W1+fb1     [w1 frags in regs]
// S2 (blk<128, (m,n)): T2[m-rows, n*16 cols] = relu(LN1(T1))@W2+fb2 (local stats)
// S3 (blk<128, (m,n)): t3 slice -> frag-major packed bf16   (local stats)
// S4 (all 256, h=blk): z += scale*(t3 @ W4[h]).dX           [W4 in regs]
// Sync: last-producer-publishes single flag line; 1 polling thread/block.
// ---------------------------------------------------------------------------
__global__ __launch_bounds__(512, 1) void k_scan(
    const short* __restrict__ W1T, const float* __restrict__ fb1,
    const float* __restrict__ g1,  const float* __restrict__ be1,
    const short* __restrict__ W2T, const float* __restrict__ fb2,
    const float* __restrict__ g2,  const float* __restrict__ be2,
    const short* __restrict__ W3T, const float* __restrict__ fb3,
    const short* __restrict__ W4T,
    const float* __restrict__ dknot, const float* __restrict__ dmid,
    float* __restrict__ z, uint* __restrict__ Xu, uint* __restrict__ t3u,
    float* __restrict__ T1, float* __restrict__ T2,
    int* __restrict__ flags) {
  const int blk = blockIdx.x;
  const int tid = threadIdx.x;
  const int wave = tid >> 6, lane = tid & 63;
  const int lm = lane & 15, q = lane >> 4;
  const int m = (blk & 127) >> 4;   // row-group, blocks 0..127
  const int n = blk & 15;           // col-slice selector
  const int ks = wave >> 2, nwt = wave & 3;

  __shared__ short t3s[B * KA];          // 72 KB
  __shared__ float red2[8][256];         //  8 KB
  __shared__ float red4[8][128];         //  4 KB
  __shared__ float zcol[128];

  // flag/counter lines (16 ints each)
  int* cS1g = flags;                 // [8*NPH]
  int* fS1g = flags + 1008 * 16;
  int* cS2g = flags + 2016 * 16;
  int* fS2g = flags + 3024 * 16;
  int* cS3  = flags + 4032 * 16;     // [NPH]
  int* fS3  = flags + 4158 * 16;
  int* cS4  = flags + 4284 * 16;
  int* fS4  = flags + 4410 * 16;

  // persistent W4 B-fragments (all blocks; h = blk)
  const int nts = (wave < 7) ? 2 : 1;
  const int nt0 = wave * 2;
  short8 bfr[2][9];
  for (int t = 0; t < nts; t++) {
    const short* wp = W4T + ((size_t)blk * CP + (nt0 + t) * 16 + lm) * KA + q * 8;
#pragma unroll
    for (int kc = 0; kc < 9; kc++)
      bfr[t][kc] = *(const short8*)(wp + kc * 32);
  }
  // persistent MLP weight fragments (blocks 0..127)
  short8 w1f[4], w2f[4], w3f;
  if (blk < 128) {
    const short* p1 = W1T + ((size_t)(n * 64 + nwt * 16 + lm)) * H + ks * 128 + q * 8;
#pragma unroll
    for (int kc = 0; kc < 4; kc++) w1f[kc] = *(const short8*)(p1 + kc * 32);
    const short* p2 = W2T + ((size_t)(n * 16 + lm)) * WMH + wave * 128 + q * 8;
#pragma unroll
    for (int kc = 0; kc < 4; kc++) w2f[kc] = *(const short8*)(p2 + kc * 32);
    w3f = *(const short8*)(W3T + ((size_t)(n * 16 + lm)) * H + wave * 32 + q * 8);
  }
  if (tid < 128) zcol[tid] = z[(size_t)tid * H + blk];
  __syncthreads();

  for (int p = 0; p < NPH; p++) {
    const int seg = p >> 1, pm = p & 1;
    const float* dX = (pm ? dmid : dknot) + (size_t)seg * B * CP;
    const float scale = pm ? HSTEP : 0.5f * HSTEP;

    // ---- S1: T1[m-rows, n*64 cols] = X @ W1 + fb1 ----
    if (blk < 128) {
      if (p) waitflag(fS4 + (p - 1) * 16, 1);
      const uint* xp = Xu + (size_t)(m * 16 + lm) * H + ks * 128 + q * 8;
      uint4v xv[8];
      CLOAD8(xv[0], xv[1], xv[2], xv[3], xv[4], xv[5], xv[6], xv[7], xp);
      f32x4 acc = {0.f, 0.f, 0.f, 0.f};
#pragma unroll
      for (int kc = 0; kc < 4; kc++) {
        short8 ah, al;
        unpk(xv[kc * 2], xv[kc * 2 + 1], ah, al);
        acc = MFMA16(ah, w1f[kc], acc);
        acc = MFMA16(al, w1f[kc], acc);
      }
#pragma unroll
      for (int r = 0; r < 4; r++) red2[wave][(q * 4 + r) * 16 + lm] = acc[r];
      __syncthreads();
      if (wave < 4) {
        int col = n * 64 + wave * 16 + lm;
        float fb = fb1[col];
#pragma unroll
        for (int r = 0; r < 4; r++) {
          int idx = (q * 4 + r) * 16 + lm;
          float v = red2[wave][idx] + red2[wave + 4][idx] + fb;
          cstoref(T1 + (size_t)(m * 16 + q * 4 + r) * WMH + col, v);
        }
      }
      siggroup(cS1g + (m * NPH + p) * 16, 16, fS1g + (m * NPH + p) * 16);
    }

    // ---- S2: T2 slice = relu(LN1(T1)) @ W2 + fb2, group-local wait ----
    if (blk < 128) {
      waitflag(fS1g + (m * NPH + p) * 16, 1);
      const float* tp = T1 + (size_t)(m * 16 + lm) * WMH + wave * 128 + q * 8;
      uint4v yv[8];
      CLOAD8(yv[0], yv[1], yv[2], yv[3], yv[4], yv[5], yv[6], yv[7], tp);
      float s = 0.f, ss = 0.f;
#pragma unroll
      for (int i = 0; i < 8; i++)
#pragma unroll
        for (int e = 0; e < 4; e++) {
          float v = __uint_as_float(yv[i][e]);
          s += v; ss += v * v;
        }
      s += __shfl_xor(s, 16); ss += __shfl_xor(ss, 16);
      s += __shfl_xor(s, 32); ss += __shfl_xor(ss, 32);
      if (q == 0) { red2[wave][lm] = s; red2[wave][16 + lm] = ss; }
      __syncthreads();
      float S = 0.f, SS = 0.f;
#pragma unroll
      for (int w = 0; w < 8; w++) { S += red2[w][lm]; SS += red2[w][16 + lm]; }
      float mean = S * (1.f / WMH);
      float var  = SS * (1.f / WMH) - mean * mean;
      float rsv  = rsqrtf(var + EPS);
      __syncthreads();
      f32x4 acc = {0.f, 0.f, 0.f, 0.f};
#pragma unroll
      for (int kc = 0; kc < 4; kc++) {
        int kg = wave * 128 + kc * 32 + q * 8;
        short8 ah, al;
#pragma unroll
        for (int jj = 0; jj < 8; jj++) {
          float v = __uint_as_float(yv[kc * 2 + (jj >> 2)][jj & 3]);
          float a = fmaxf((v - mean) * rsv * g1[kg + jj] + be1[kg + jj], 0.f);
          short hi = f2bf(a);
          ah[jj] = hi;
          al[jj] = f2bf(a - bf2f(hi));
        }
        acc = MFMA16(ah, w2f[kc], acc);
        acc = MFMA16(al, w2f[kc], acc);
      }
#pragma unroll
      for (int r = 0; r < 4; r++) red2[wave][(q * 4 + r) * 16 + lm] = acc[r];
      __syncthreads();
      if (tid < 256) {
        int ri = tid >> 4, ci = tid & 15;
        float v = fb2[n * 16 + ci];
#pragma unroll
        for (int w = 0; w < 8; w++) v += red2[w][tid];
        cstoref(T2 + (size_t)(m * 16 + ri) * H + n * 16 + ci, v);
      }
      siggroup(cS2g + (m * NPH + p) * 16, 16, fS2g + (m * NPH + p) * 16);
    }

    // ---- S3: t3 slice -> frag-major packed bf16, group-local wait ----
    if (blk < 128) {
      waitflag(fS2g + (m * NPH + p) * 16, 1);
      const float* tp = T2 + (size_t)(m * 16 + lm) * H + wave * 32 + q * 8;
      uint4v u0, u1;
      CLOAD2(u0, u1, tp);
      float s = 0.f, ss = 0.f;
#pragma unroll
      for (int e = 0; e < 4; e++) {
        float v0 = __uint_as_float(u0[e]), v1 = __uint_as_float(u1[e]);
        s += v0 + v1; ss += v0 * v0 + v1 * v1;
      }
      s += __shfl_xor(s, 16); ss += __shfl_xor(ss, 16);
      s += __shfl_xor(s, 32); ss += __shfl_xor(ss, 32);
      if (q == 0) { red2[wave][lm] = s; red2[wave][16 + lm] = ss; }
      __syncthreads();
      float S = 0.f, SS = 0.f;
#pragma unroll
      for (int w = 0; w < 8; w++) { S += red2[w][lm]; SS += red2[w][16 + lm]; }
      float mean = S * (1.f / H);
      float var  = SS * (1.f / H) - mean * mean;
      float rsv  = rsqrtf(var + EPS);
      __syncthreads();
      int kg = wave * 32 + q * 8;
      short8 ah, al;
#pragma unroll
      for (int jj = 0; jj < 8; jj++) {
        float v = __uint_as_float((jj < 4 ? u0[jj & 3] : u1[jj & 3]));
        float a = fmaxf((v - mean) * rsv * g2[kg + jj] + be2[kg + jj], 0.f);
        short hi = f2bf(a);
        ah[jj] = hi;
        al[jj] = f2bf(a - bf2f(hi));
      }
      f32x4 acc = {0.f, 0.f, 0.f, 0.f};
      acc = MFMA16(ah, w3f, acc);
      acc = MFMA16(al, w3f, acc);
#pragma unroll
      for (int r = 0; r < 4; r++) red2[wave][(q * 4 + r) * 16 + lm] = acc[r];
      __syncthreads();
      if (tid < 256) {
        int ri = tid >> 4, ci = tid & 15;
        float v = fb3[n * 16 + ci];
#pragma unroll
        for (int w = 0; w < 8; w++) v += red2[w][tid];
        v = fmaxf(v, 0.f);
        float vo = __shfl_xor(v, 1);
        if ((ci & 1) == 0) {
          int kglob = n * 16 + ci;
          int d = (m * 9 + (kglob >> 5)) * 64 + ((kglob >> 3) & 3) * 16 + ri;
          uint u = ((uint)(unsigned short)f2bf(vo) << 16)
                 | (unsigned short)f2bf(v);
          cstoreu(t3u + d * 4 + ((kglob & 7) >> 1), u);
        }
      }
      siggroup(cS3 + p * 16, 128, fS3 + p * 16);
    }

    // ---- S4: all 256 blocks, h = blk ----
    {
      waitflag(fS3 + p * 16, 1);
#pragma unroll
      for (int g = 0; g < 3; g++) {
        const uint* a0 = t3u + (g * 3 + 0) * 2048 + tid * 4;
        const uint* a1 = t3u + (g * 3 + 1) * 2048 + tid * 4;
        const uint* a2 = t3u + (g * 3 + 2) * 2048 + tid * 4;
        uint4v r0, r1, r2;
        CLOAD3A(r0, r1, r2, a0, a1, a2);
        *(uint4v*)(t3s + (size_t)((g * 3 + 0) * 2048 + tid * 4) * 2) = r0;
        *(uint4v*)(t3s + (size_t)((g * 3 + 1) * 2048 + tid * 4) * 2) = r1;
        *(uint4v*)(t3s + (size_t)((g * 3 + 2) * 2048 + tid * 4) * 2) = r2;
      }
      __syncthreads();
      for (int mm = 0; mm < 8; mm++) {
        short8 afr[9];
#pragma unroll
        for (int kc = 0; kc < 9; kc++)
          afr[kc] = *(const short8*)(t3s + (size_t)((mm * 9 + kc) * 64 + lane) * 8);
        f32x4 acc0 = {0.f, 0.f, 0.f, 0.f}, acc1 = {0.f, 0.f, 0.f, 0.f};
#pragma unroll
        for (int kc = 0; kc < 9; kc++) {
          acc0 = MFMA16(afr[kc], bfr[0][kc], acc0);
          if (nts > 1) acc1 = MFMA16(afr[kc], bfr[1][kc], acc1);
        }
        float part[4];
#pragma unroll
        for (int r = 0; r < 4; r++) {
          int row = mm * 16 + q * 4 + r;
          float pv = acc0[r] * dX[(size_t)row * CP + nt0 * 16 + lm];
          if (nts > 1) pv += acc1[r] * dX[(size_t)row * CP + (nt0 + 1) * 16 + lm];
          part[r] = pv;
        }
#pragma unroll
        for (int r = 0; r < 4; r++) {
          part[r] += __shfl_xor(part[r], 1);
          part[r] += __shfl_xor(part[r], 2);
          part[r] += __shfl_xor(part[r], 4);
          part[r] += __shfl_xor(part[r], 8);
        }
        if (lm == 0) {
#pragma unroll
          for (int r = 0; r < 4; r++) red4[wave][mm * 16 + q * 4 + r] = part[r];
        }
      }
      __syncthreads();
      if (tid < 128) {
        int row = tid;
        float s = 0.f;
#pragma unroll
        for (int w = 0; w < 8; w++) s += red4[w][row];
        float zo = zcol[row] + scale * s;
        if (pm) zcol[row] = zo;
        if (p == NPH - 1) z[(size_t)row * H + blk] = zo;
        short hi = f2bf(zo);
        short lo = f2bf(zo - bf2f(hi));
        cstoreu(Xu + (size_t)row * H + blk,
                ((uint)(unsigned short)hi << 16) | (unsigned short)lo);
      }
      siggroup(cS4 + p * 16, 256, fS4 + p * 16);
    }
  }
}

// ---------------------------------------------------------------------------
// Kernel 6: output heads
// ---------------------------------------------------------------------------
__global__ __launch_bounds__(256) void k_final(const float* __restrict__ z,
    const float* __restrict__ yW1, const float* __restrict__ yb1,
    const float* __restrict__ yW2, const float* __restrict__ yb2,
    const float* __restrict__ zW1, const float* __restrict__ zb1,
    const float* __restrict__ zW2, const float* __restrict__ zb2,
    float* __restrict__ out) {
  __shared__ float ht[H];
  __shared__ float ry[128];
  __shared__ float rz[H];
  int b = blockIdx.x, tid = threadIdx.x;
  ht[tid] = z[(size_t)b * H + tid];
  __syncthreads();
  if (tid < 128) {
    float s = yb1[tid];
    for (int k = 0; k < H; k++) s += ht[k] * yW1[k * 128 + tid];
    ry[tid] = fmaxf(s, 0.f);
  }
  {
    float s = zb1[tid];
    for (int k = 0; k < H; k++) s += ht[k] * zW1[k * H + tid];
    rz[tid] = fmaxf(s, 0.f);
  }
  __syncthreads();
  if (tid < 64) {
    float sv = ry[tid] * yW2[tid] + ry[tid + 64] * yW2[tid + 64];
    for (int off = 32; off > 0; off >>= 1) sv += __shfl_down(sv, off);
    if (tid == 0) out[b] = sv + yb2[0];
  }
  if (tid < D) {
    float s = zb2[tid];
    for (int k = 0; k < H; k++) s += rz[k] * zW2[k * D + tid];
    out[B + b * D + tid] = s;
  }
  out[B + B * D + (size_t)b * H + tid] = ht[tid];
}

// ---------------------------------------------------------------------------
extern "C" void kernel_launch(void* const* d_in, const int* in_sizes, int n_in,
                              void* d_out, int out_size, void* d_ws, size_t ws_size,
                              hipStream_t stream) {
  const float* x   = (const float*)d_in[0];
  const float* hW1 = (const float*)d_in[1];
  const float* hb1 = (const float*)d_in[2];
  const float* hW2 = (const float*)d_in[3];
  const float* hb2 = (const float*)d_in[4];
  const float* fW1 = (const float*)d_in[5];
  const float* fb1 = (const float*)d_in[6];
  const float* g1  = (const float*)d_in[7];
  const float* be1 = (const float*)d_in[8];
  const float* fW2 = (const float*)d_in[9];
  const float* fb2 = (const float*)d_in[10];
  const float* g2  = (const float*)d_in[11];
  const float* be2 = (const float*)d_in[12];
  const float* fW3 = (const float*)d_in[13];
  const float* fb3 = (const float*)d_in[14];
  const float* fW4 = (const float*)d_in[15];
  const float* fb4 = (const float*)d_in[16];
  const float* yW1 = (const float*)d_in[17];
  const float* yb1 = (const float*)d_in[18];
  const float* yW2 = (const float*)d_in[19];
  const float* yb2 = (const float*)d_in[20];
  const float* zW1 = (const float*)d_in[21];
  const float* zb1 = (const float*)d_in[22];
  const float* zW2 = (const float*)d_in[23];
  const float* zb2 = (const float*)d_in[24];
  const float* sg  = (const float*)d_in[25];
  const float* sb  = (const float*)d_in[26];

  float* ws     = (float*)d_ws;
  float* dknot  = ws;                               // 1,935,360 f
  float* dmid   = dknot + (size_t)NSEG * B * CP;    // 1,935,360 f
  float* z      = dmid + (size_t)NSEG * B * CP;     // 32,768 f
  float* T1     = z + B * H;                        // 131,072 f
  float* T2     = T1 + B * WMH;                     // 32,768 f
  uint* Xu      = (uint*)(T2 + B * H);              // 32,768 u
  uint* t3u     = Xu + B * H;                       // 18,432 u
  int* flags    = (int*)(t3u + B * KA / 2);         // 72,576 i (4536 lines)
  short* w1T    = (short*)(flags + 72576);          // 262,144 s
  short* w2T    = w1T + H * WMH;                    // 262,144 s
  short* w3T    = w2T + H * WMH;                    // 65,536 s
  short* W4T    = w3T + H * H;                      // 17,694,720 s
  float* y      = (float*)W4T;                      // temp alias (dead before W4T built)

  hipLaunchKernelGGL(k_logsig, dim3(B), dim3(256), 0, stream, x, sg, sb, y);
  hipLaunchKernelGGL(k_spline, dim3(B), dim3(256), 0, stream, y, dknot, dmid);
  hipLaunchKernelGGL(k_h0,     dim3(B), dim3(256), 0, stream, x, hW1, hb1, hW2, hb2, z, Xu);
  hipLaunchKernelGGL(k_prep_t,   dim3(928, 4), dim3(256), 0, stream, fW4, W4T);
  hipLaunchKernelGGL(k_prep_pad, dim3(9728),   dim3(256), 0, stream, fb4, W4T);
  hipLaunchKernelGGL(k_prep_wt,  dim3(16, 4),  dim3(256), 0, stream, fW1, w1T, H, WMH);
  hipLaunchKernelGGL(k_prep_wt,  dim3(4, 16),  dim3(256), 0, stream, fW2, w2T, WMH, H);
  hipLaunchKernelGGL(k_prep_wt,  dim3(4, 4),   dim3(256), 0, stream, fW3, w3T, H, H);
  hipLaunchKernelGGL(k_prep_t3pad, dim3(1), dim3(128), 0, stream, (short*)t3u);
  hipLaunchKernelGGL(k_prep_zero, dim3(284), dim3(256), 0, stream, flags, 72576);

  void* args[] = {
    (void*)&w1T, (void*)&fb1, (void*)&g1, (void*)&be1,
    (void*)&w2T, (void*)&fb2, (void*)&g2, (void*)&be2,
    (void*)&w3T, (void*)&fb3, (void*)&W4T,
    (void*)&dknot, (void*)&dmid,
    (void*)&z, (void*)&Xu, (void*)&t3u,
    (void*)&T1, (void*)&T2, (void*)&flags
  };
  hipLaunchCooperativeKernel((const void*)k_scan, dim3(256), dim3(512), args, 0, stream);

  hipLaunchKernelGGL(k_final, dim3(B), dim3(256), 0, stream, z,
                     yW1, yb1, yW2, yb2, zW1, zb1, zW2, zb2, (float*)d_out);
}